// Round 11
// baseline (524.330 us; speedup 1.0000x reference)
//
#include <hip/hip_runtime.h>
#include <math.h>

#define DEVI static __device__ __forceinline__

typedef __attribute__((ext_vector_type(8))) short short8;
typedef __attribute__((ext_vector_type(4))) float f32x4;
typedef unsigned short u16;

DEVI float gelu_f(float x) {
    return 0.5f * x * (1.0f + erff(x * 0.7071067811865475f));
}
DEVI u16 f2bf(float f) {
    unsigned u = __builtin_bit_cast(unsigned, f);
    return (u16)((u + 0x7fffu + ((u >> 16) & 1u)) >> 16);
}
DEVI float bf2f(u16 b) {
    unsigned u = ((unsigned)b) << 16;
    return __builtin_bit_cast(float, u);
}
DEVI void split_bf(float v, u16& h, u16& l) {
    h = f2bf(v);
    l = f2bf(v - bf2f(h));
}

// ---------------------------------------------------------------------------
// Plane GEMM (R6/R10-proven inner loop — no cross-barrier register prefetch:
// lambda-captured prefetch arrays spill to scratch, rule #20 / R9 post-mortem).
// C[M,N] = act((Ah+Al)[M,K] @ (Bh+Bl)[N,K]^T + bias); SPLIT = 3-MFMA product.
// Block 256 thr / 4 waves, tile 128xBN, BK=64, LDS rows padded to 72 shorts.
// OMODE: 0 f32 out; 1 planes out;
//        3 fused QKV (Q planes | K planes | V transposed planes) — B operand
//          MUST be the CONCATENATED [2*partN + HH*128][K] weight planes;
//        4 col<partN: column-MAX partials -> Cf[32][partN];
//          col>=partN: gelu planes -> O1 (stride partN);
//        5 planes out (gelu) + column-SUM partials -> Cf[32][N].
// Partial reductions are fixed-order (deterministic).
// ---------------------------------------------------------------------------
template<int BN, bool SPLIT, bool DO_GELU, int OMODE>
__global__ __launch_bounds__(256, 2)
void gemm_planes(const u16* __restrict__ Agh, const u16* __restrict__ Agl,
                 const u16* __restrict__ Bgh, const u16* __restrict__ Bgl,
                 const float* __restrict__ bias, float* __restrict__ Cf,
                 u16* __restrict__ O1h, u16* __restrict__ O1l,
                 u16* __restrict__ O2h, u16* __restrict__ O2l,
                 u16* __restrict__ O3h, u16* __restrict__ O3l,
                 int M, int N, int K, int HH, int partN)
{
    constexpr int BM = 128, BK = 64, PK = 72;
    constexpr int NPL = SPLIT ? 2 : 1;
    constexpr int MF  = (BN == 128) ? 4 : 2;
    constexpr int NB  = BN / 32;
    __shared__ __align__(16) u16 As[NPL][BM * PK];
    __shared__ __align__(16) u16 Bs[NPL][BN * PK];
    const int t = threadIdx.x, w = t >> 6, l = t & 63;
    const int lr = l & 15, lg = l >> 4;
    const int m0 = blockIdx.y * BM, n0 = blockIdx.x * BN;
    const int moff = (BN == 128) ? (w >> 1) * 64 : w * 32;
    const int noff = (BN == 128) ? (w & 1) * 64 : 0;
    const int srow = t >> 3, sslot = t & 7;

    f32x4 acc[MF][4];
    #pragma unroll
    for (int i = 0; i < MF; ++i)
        #pragma unroll
        for (int j = 0; j < 4; ++j) acc[i][j] = 0.0f;

    for (int k0 = 0; k0 < K; k0 += BK) {
        __syncthreads();   // previous tile fully consumed
        #pragma unroll
        for (int p = 0; p < 4; ++p) {
            int row = p * 32 + srow;
            size_t g = (size_t)(m0 + row) * K + k0 + sslot * 8;
            *(uint4*)&As[0][row * PK + sslot * 8] = *(const uint4*)&Agh[g];
            if constexpr (SPLIT)
                *(uint4*)&As[1][row * PK + sslot * 8] = *(const uint4*)&Agl[g];
        }
        #pragma unroll
        for (int p = 0; p < NB; ++p) {
            int row = p * 32 + srow;
            size_t g = (size_t)(n0 + row) * K + k0 + sslot * 8;
            *(uint4*)&Bs[0][row * PK + sslot * 8] = *(const uint4*)&Bgh[g];
            if constexpr (SPLIT)
                *(uint4*)&Bs[1][row * PK + sslot * 8] = *(const uint4*)&Bgl[g];
        }
        __syncthreads();
        #pragma unroll
        for (int ks = 0; ks < 2; ++ks) {
            short8 af[MF][NPL], bfr[4][NPL];
            #pragma unroll
            for (int mf = 0; mf < MF; ++mf) {
                int a = (moff + mf * 16 + lr) * PK + ks * 32 + lg * 8;
                af[mf][0] = *(const short8*)&As[0][a];
                if constexpr (SPLIT) af[mf][1] = *(const short8*)&As[1][a];
            }
            #pragma unroll
            for (int nf = 0; nf < 4; ++nf) {
                int a = (noff + nf * 16 + lr) * PK + ks * 32 + lg * 8;
                bfr[nf][0] = *(const short8*)&Bs[0][a];
                if constexpr (SPLIT) bfr[nf][1] = *(const short8*)&Bs[1][a];
            }
            #pragma unroll
            for (int mf = 0; mf < MF; ++mf)
                #pragma unroll
                for (int nf = 0; nf < 4; ++nf) {
                    acc[mf][nf] = __builtin_amdgcn_mfma_f32_16x16x32_bf16(
                        af[mf][0], bfr[nf][0], acc[mf][nf], 0, 0, 0);
                    if constexpr (SPLIT) {
                        acc[mf][nf] = __builtin_amdgcn_mfma_f32_16x16x32_bf16(
                            af[mf][0], bfr[nf][1], acc[mf][nf], 0, 0, 0);
                        acc[mf][nf] = __builtin_amdgcn_mfma_f32_16x16x32_bf16(
                            af[mf][1], bfr[nf][0], acc[mf][nf], 0, 0, 0);
                    }
                }
        }
    }

    // ---- epilogue: C row = lg*4+r, col = lr within each 16x16 subtile ----
    float colred[4];
    if constexpr (OMODE == 4) {
        colred[0] = colred[1] = colred[2] = colred[3] = -3.402823466e38f;
    } else if constexpr (OMODE == 5) {
        colred[0] = colred[1] = colred[2] = colred[3] = 0.0f;
    }
    #pragma unroll
    for (int mf = 0; mf < MF; ++mf)
        #pragma unroll
        for (int nf = 0; nf < 4; ++nf) {
            int col  = n0 + noff + nf * 16 + lr;
            int mrow = m0 + moff + mf * 16 + lg * 4;
            float bv = bias ? bias[col] : 0.0f;
            float ov[4];
            #pragma unroll
            for (int r = 0; r < 4; ++r) ov[r] = acc[mf][nf][r] + bv;
            if constexpr (OMODE == 0) {
                #pragma unroll
                for (int r = 0; r < 4; ++r) {
                    float o = ov[r];
                    if constexpr (DO_GELU) o = gelu_f(o);
                    Cf[(size_t)(mrow + r) * N + col] = o;
                }
            } else if constexpr (OMODE == 1) {
                #pragma unroll
                for (int r = 0; r < 4; ++r) {
                    float o = ov[r];
                    if constexpr (DO_GELU) o = gelu_f(o);
                    u16 hb, lb; split_bf(o, hb, lb);
                    O1h[(size_t)(mrow + r) * N + col] = hb;
                    O1l[(size_t)(mrow + r) * N + col] = lb;
                }
            } else if constexpr (OMODE == 3) {
                if (col < partN) {
                    #pragma unroll
                    for (int r = 0; r < 4; ++r) {
                        u16 hb, lb; split_bf(ov[r], hb, lb);
                        O1h[(size_t)(mrow + r) * partN + col] = hb;
                        O1l[(size_t)(mrow + r) * partN + col] = lb;
                    }
                } else if (col < 2 * partN) {
                    int c2 = col - partN;
                    #pragma unroll
                    for (int r = 0; r < 4; ++r) {
                        u16 hb, lb; split_bf(ov[r], hb, lb);
                        O2h[(size_t)(mrow + r) * partN + c2] = hb;
                        O2l[(size_t)(mrow + r) * partN + c2] = lb;
                    }
                } else {
                    int c2 = col - 2 * partN;
                    int hh = c2 >> 7, dd = c2 & 127;
                    int bb = mrow >> 10, s0 = mrow & 1023;
                    size_t idx = ((size_t)(bb * HH + hh) * 128 + dd) * 1024 + s0;
                    ushort4 oh, ol;
                    #pragma unroll
                    for (int r = 0; r < 4; ++r) {
                        u16 hb, lb; split_bf(ov[r], hb, lb);
                        ((u16*)&oh)[r] = hb; ((u16*)&ol)[r] = lb;
                    }
                    *(ushort4*)&O3h[idx] = oh;
                    *(ushort4*)&O3l[idx] = ol;
                }
            } else if constexpr (OMODE == 4) {
                if (n0 < partN) {
                    #pragma unroll
                    for (int r = 0; r < 4; ++r)
                        colred[nf] = fmaxf(colred[nf], ov[r]);
                } else {
                    int c2 = col - partN;
                    #pragma unroll
                    for (int r = 0; r < 4; ++r) {
                        float o = gelu_f(ov[r]);
                        u16 hb, lb; split_bf(o, hb, lb);
                        O1h[(size_t)(mrow + r) * partN + c2] = hb;
                        O1l[(size_t)(mrow + r) * partN + c2] = lb;
                    }
                }
            } else if constexpr (OMODE == 5) {
                #pragma unroll
                for (int r = 0; r < 4; ++r) {
                    float o = gelu_f(ov[r]);
                    colred[nf] += o;
                    u16 hb, lb; split_bf(o, hb, lb);
                    O1h[(size_t)(mrow + r) * N + col] = hb;
                    O1l[(size_t)(mrow + r) * N + col] = lb;
                }
            }
        }
    // ---- fixed-order per-block column reduction (deterministic) ----
    if constexpr (OMODE == 4 || OMODE == 5) {
        bool doRed = (OMODE == 5) || (n0 < partN);
        if (doRed) {
            __syncthreads();
            float* sred = (float*)&As[0][0];   // 4 KB scratch, tile dead
            #pragma unroll
            for (int nf = 0; nf < 4; ++nf) sred[t * 4 + nf] = colred[nf];
            __syncthreads();
            if (t < 128) {
                int cl = t, lrr = cl & 15, nff = (cl & 63) >> 4, wb = cl >> 6;
                float a = (OMODE == 4) ? -3.402823466e38f : 0.0f;
                #pragma unroll
                for (int k2 = 0; k2 < 2; ++k2)
                    #pragma unroll
                    for (int l2 = 0; l2 < 4; ++l2) {
                        float v = sred[(((wb + 2 * k2) * 64) + l2 * 16 + lrr) * 4 + nff];
                        if constexpr (OMODE == 4) a = fmaxf(a, v); else a += v;
                    }
                int stride = (OMODE == 4) ? partN : N;
                Cf[(size_t)blockIdx.y * stride + n0 + cl] = a;
            }
        }
    }
}

// ---------------------------------------------------------------------------
// Plane flash attention (R4-proven math) + XCD swizzle (T1), templated on
// wave count NW: block = NW*64 threads, q-tile = NW*16 rows. NW=4 is the
// exact R10 router config; NW=2 doubles the grid for the grid-starved input
// attention (512 blocks, 43 KB LDS -> 3 blocks/CU, independent barrier
// domains overlap staging with compute).
// ---------------------------------------------------------------------------
template<int NW>
__global__ __launch_bounds__(NW * 64, (NW == 4) ? 3 : 2)
void attn_planes(const u16* __restrict__ Qh, const u16* __restrict__ Ql,
                 const u16* __restrict__ Kh, const u16* __restrict__ Kl,
                 const u16* __restrict__ Vh, const u16* __restrict__ Vl,
                 u16* __restrict__ Oh, u16* __restrict__ Ol,
                 int S, int Dm, int H, float scale)
{
    constexpr int NT = NW * 64;          // threads
    constexpr int KIT = 512 / NT;        // staging iters (32x16 uint4 slots)
    __shared__ __align__(16) u16 KsL[2][32 * 136];
    __shared__ __align__(16) u16 VsL[2][128 * 40];
    __shared__ __align__(16) u16 PsL[2][NW * 16 * 40];
    const int t = threadIdx.x, w = t >> 6, l = t & 63;
    const int lr = l & 15, lg = l >> 4;
    const int nqt = gridDim.x;
    const int nwg = nqt * gridDim.y;
    const int fid = blockIdx.y * nqt + blockIdx.x;
    const int nid = (fid & 7) * (nwg >> 3) + (fid >> 3);
    const int bh = nid / nqt, qt = nid - bh * nqt;
    const int b = bh / H, h = bh - b * H;
    const int q0 = qt * (NW * 16) + w * 16;
    const size_t qkbase = (size_t)(b * S) * Dm + h * 128;
    const size_t vbase  = (size_t)(b * H + h) * 128 * 1024;

    short8 qhf[4], qlf[4];
    #pragma unroll
    for (int ks = 0; ks < 4; ++ks) {
        size_t g = qkbase + (size_t)(q0 + lr) * Dm + ks * 32 + lg * 8;
        qhf[ks] = *(const short8*)&Qh[g];
        qlf[ks] = *(const short8*)&Ql[g];
    }
    f32x4 accO[8];
    #pragma unroll
    for (int i = 0; i < 8; ++i) accO[i] = 0.0f;
    float ls = 0.0f;
    const int pw = w * 640;

    for (int c0 = 0; c0 < S; c0 += 32) {
        __syncthreads();
        #pragma unroll
        for (int p = 0; p < KIT; ++p) {       // K: 32 keys x 16 slots
            int idx = p * NT + t;
            int key = idx >> 4, slot = idx & 15;
            size_t g = qkbase + (size_t)(c0 + key) * Dm + slot * 8;
            *(uint4*)&KsL[0][key * 136 + slot * 8] = *(const uint4*)&Kh[g];
            *(uint4*)&KsL[1][key * 136 + slot * 8] = *(const uint4*)&Kl[g];
        }
        #pragma unroll
        for (int p = 0; p < KIT; ++p) {       // V^T: 128 d x 4 key-slots
            int idx = p * NT + t;
            int d = idx >> 2, ksl = idx & 3;
            size_t g = vbase + (size_t)d * 1024 + c0 + ksl * 8;
            *(uint4*)&VsL[0][d * 40 + ksl * 8] = *(const uint4*)&Vh[g];
            *(uint4*)&VsL[1][d * 40 + ksl * 8] = *(const uint4*)&Vl[g];
        }
        __syncthreads();
        f32x4 sac[2];
        sac[0] = 0.0f; sac[1] = 0.0f;
        #pragma unroll
        for (int mt = 0; mt < 2; ++mt)
            #pragma unroll
            for (int ks = 0; ks < 4; ++ks) {
                int a = (mt * 16 + lr) * 136 + ks * 32 + lg * 8;
                short8 khf = *(const short8*)&KsL[0][a];
                short8 klf = *(const short8*)&KsL[1][a];
                sac[mt] = __builtin_amdgcn_mfma_f32_16x16x32_bf16(khf, qhf[ks], sac[mt], 0, 0, 0);
                sac[mt] = __builtin_amdgcn_mfma_f32_16x16x32_bf16(khf, qlf[ks], sac[mt], 0, 0, 0);
                sac[mt] = __builtin_amdgcn_mfma_f32_16x16x32_bf16(klf, qhf[ks], sac[mt], 0, 0, 0);
            }
        #pragma unroll
        for (int mt = 0; mt < 2; ++mt)
            #pragma unroll
            for (int rr = 0; rr < 4; ++rr) {
                float p = __expf(sac[mt][rr] * scale);
                ls += p;
                int key = mt * 16 + lg * 4 + rr;
                u16 hb, lb; split_bf(p, hb, lb);
                PsL[0][pw + lr * 40 + key] = hb;
                PsL[1][pw + lr * 40 + key] = lb;
            }
        short8 pah = *(const short8*)&PsL[0][pw + lr * 40 + lg * 8];
        short8 pal = *(const short8*)&PsL[1][pw + lr * 40 + lg * 8];
        #pragma unroll
        for (int nt = 0; nt < 8; ++nt) {
            int a = (nt * 16 + lr) * 40 + lg * 8;
            short8 vhf = *(const short8*)&VsL[0][a];
            short8 vlf = *(const short8*)&VsL[1][a];
            accO[nt] = __builtin_amdgcn_mfma_f32_16x16x32_bf16(pah, vhf, accO[nt], 0, 0, 0);
            accO[nt] = __builtin_amdgcn_mfma_f32_16x16x32_bf16(pah, vlf, accO[nt], 0, 0, 0);
            accO[nt] = __builtin_amdgcn_mfma_f32_16x16x32_bf16(pal, vhf, accO[nt], 0, 0, 0);
        }
    }
    float lt = ls + __shfl_xor(ls, 16, 64);
    lt += __shfl_xor(lt, 32, 64);
    #pragma unroll
    for (int rr = 0; rr < 4; ++rr) {
        float inv = 1.0f / __shfl(lt, lg * 4 + rr, 64);
        size_t rowoff = qkbase + (size_t)(q0 + lg * 4 + rr) * Dm;
        #pragma unroll
        for (int nt = 0; nt < 8; ++nt) {
            float o = accO[nt][rr] * inv;
            u16 hb, lb; split_bf(o, hb, lb);
            Oh[rowoff + nt * 16 + lr] = hb;
            Ol[rowoff + nt * 16 + lr] = lb;
        }
    }
}

// ---------------------------------------------------------------------------
// Multi-segment packer: fp32 -> bf16 hi/lo planes. n4 = count of float4s.
// ---------------------------------------------------------------------------
struct PSeg { const float* s; u16* h; u16* l; int n4; int pad; };
struct PArgs { PSeg g[8]; };

__global__ __launch_bounds__(256)
void pack_many(PArgs a)
{
    PSeg sg = a.g[blockIdx.y];
    int i = blockIdx.x * 256 + threadIdx.x;
    if (i >= sg.n4) return;
    float4 v = *(const float4*)&sg.s[i * 4];
    ushort4 hv, lv;
    split_bf(v.x, hv.x, lv.x);
    split_bf(v.y, hv.y, lv.y);
    split_bf(v.z, hv.z, lv.z);
    split_bf(v.w, hv.w, lv.w);
    *(ushort4*)&sg.h[i * 4] = hv;
    *(ushort4*)&sg.l[i * 4] = lv;
}

__global__ __launch_bounds__(256)
void pack_f32(const float* __restrict__ src, u16* __restrict__ dh,
              u16* __restrict__ dl, int n4)
{
    int i = blockIdx.x * 256 + threadIdx.x;
    if (i >= n4) return;
    float4 v = *(const float4*)&src[i * 4];
    ushort4 hv, lv;
    split_bf(v.x, hv.x, lv.x);
    split_bf(v.y, hv.y, lv.y);
    split_bf(v.z, hv.z, lv.z);
    split_bf(v.w, hv.w, lv.w);
    *(ushort4*)&dh[i * 4] = hv;
    *(ushort4*)&dl[i * 4] = lv;
}

__global__ __launch_bounds__(256)
void packT64(const float* __restrict__ src, u16* __restrict__ dh,
             u16* __restrict__ dl, int R, int C)
{
    __shared__ float tile[64][65];
    int r0 = blockIdx.y * 64, c0 = blockIdx.x * 64;
    int t = threadIdx.x;
    #pragma unroll
    for (int i = 0; i < 16; ++i) {
        int idx = i * 256 + t, rr = idx >> 6, cc = idx & 63;
        tile[rr][cc] = src[(size_t)(r0 + rr) * C + c0 + cc];
    }
    __syncthreads();
    #pragma unroll
    for (int i = 0; i < 16; ++i) {
        int idx = i * 256 + t, rr = idx >> 6, cc = idx & 63;
        float v = tile[cc][rr];
        u16 hb, lb; split_bf(v, hb, lb);
        size_t o = (size_t)(c0 + rr) * R + r0 + cc;
        dh[o] = hb; dl[o] = lb;
    }
}

// concat biases: rbias[3072], ibias[1536], apbias[1024] (aff_b | zeros)
__global__ __launch_bounds__(1024)
void concat_bias(const float* rq, const float* rk, const float* rv,
                 const float* iq, const float* ik, const float* iv,
                 const float* ab, float* rb, float* ib, float* apb)
{
    int t = threadIdx.x;
    rb[t]        = rq[t];
    rb[1024 + t] = rk[t];
    rb[2048 + t] = rv[t];
    apb[t] = (t < 512) ? ab[t] : 0.0f;
    if (t < 512) {
        ib[t]        = iq[t];
        ib[512 + t]  = ik[t];
        ib[1024 + t] = iv[t];
    }
}

__global__ __launch_bounds__(256)
void mask_rows(u16* __restrict__ ph, const float* __restrict__ mask)
{
    int i = blockIdx.x * 256 + threadIdx.x;
    int i4 = i * 4;
    int bb = i4 >> 20;
    int col = i4 & 1023;
    ushort4 v = *(ushort4*)&ph[i4];
    float4 m = *(const float4*)&mask[bb * 1024 + col];
    if (m.x == 0.f) v.x = 0;
    if (m.y == 0.f) v.y = 0;
    if (m.z == 0.f) v.z = 0;
    if (m.w == 0.f) v.w = 0;
    *(ushort4*)&ph[i4] = v;
}

// ---------------------------------------------------------------------------
// Fused partial-reduce (8 row-blocks, fixed order) + top-K mask via RANK
// COUNTING: rank(i) = #{v_j > v_i} + #{v_j == v_i, j < i}; mask = rank < K.
// Identical tie semantics to jax.lax.top_k (val desc, idx asc). Replaces the
// 45-barrier bitonic sort + separate reduce8 dispatch. OP: 0=max, 1=sum
// (positive scale on sums is rank-invariant, so no 1/S factor needed).
// Block = N threads, grid = B.
// ---------------------------------------------------------------------------
template<int N, int KSEL, int OP>
__global__ __launch_bounds__(1024)
void topk_rank(const float* __restrict__ P, float* __restrict__ mask)
{
    __shared__ float v[N];
    int t = threadIdx.x, b = blockIdx.x;
    float a = (OP == 0) ? -3.402823466e38f : 0.0f;
    #pragma unroll
    for (int r = 0; r < 8; ++r) {
        float x = P[(size_t)(b * 8 + r) * N + t];
        if (OP == 0) a = fmaxf(a, x); else a += x;
    }
    v[t] = a;
    __syncthreads();
    int rank = 0;
    for (int j = 0; j < N; ++j) {
        float vj = v[j];                    // LDS broadcast (conflict-free)
        rank += (vj > a) || (vj == a && j < t);
    }
    mask[b * N + t] = (rank < KSEL) ? 1.0f : 0.0f;
}

__global__ __launch_bounds__(256)
void ln_mask_planes(const u16* __restrict__ Xh, const u16* __restrict__ Xl,
                    const u16* __restrict__ Rh, const u16* __restrict__ Rl,
                    const float* __restrict__ gam, const float* __restrict__ bet,
                    const float* __restrict__ mask,
                    u16* __restrict__ Yh, u16* __restrict__ Yl)
{
    int row = blockIdx.x, bb = row >> 10, t = threadIdx.x;
    size_t base = (size_t)row * 512;
    float a1 = bf2f(Xh[base + t]) + bf2f(Xl[base + t])
             + bf2f(Rh[base + t]) + bf2f(Rl[base + t]);
    float a2 = bf2f(Xh[base + t + 256]) + bf2f(Xl[base + t + 256])
             + bf2f(Rh[base + t + 256]) + bf2f(Rl[base + t + 256]);
    float s  = a1 + a2;
    float sq = a1 * a1 + a2 * a2;
    #pragma unroll
    for (int off = 32; off > 0; off >>= 1) {
        s  += __shfl_down(s, off, 64);
        sq += __shfl_down(sq, off, 64);
    }
    __shared__ float red[8];
    int wid = t >> 6, lane = t & 63;
    if (lane == 0) { red[wid] = s; red[wid + 4] = sq; }
    __syncthreads();
    if (t == 0) {
        float st  = red[0] + red[1] + red[2] + red[3];
        float sqt = red[4] + red[5] + red[6] + red[7];
        float mu  = st / 512.0f;
        float var = sqt / 512.0f - mu * mu;
        red[0] = mu;
        red[1] = rsqrtf(var + 1e-5f);
    }
    __syncthreads();
    float mu = red[0], rstd = red[1];
    float y1 = ((a1 - mu) * rstd * gam[t] + bet[t]) * mask[bb * 512 + t];
    float y2 = ((a2 - mu) * rstd * gam[t + 256] + bet[t + 256]) * mask[bb * 512 + t + 256];
    u16 hb, lb;
    split_bf(y1, hb, lb); Yh[base + t] = hb;       Yl[base + t] = lb;
    split_bf(y2, hb, lb); Yh[base + t + 256] = hb; Yl[base + t + 256] = lb;
}

// ---------------------------------------------------------------------------
extern "C" void kernel_launch(void* const* d_in, const int* in_sizes, int n_in,
                              void* d_out, int out_size, void* d_ws, size_t ws_size,
                              hipStream_t stream)
{
    (void)in_sizes; (void)n_in; (void)out_size; (void)ws_size;
    const float* x        = (const float*)d_in[0];
    const float* r_wq     = (const float*)d_in[1];
    const float* r_wk     = (const float*)d_in[2];
    const float* r_wv     = (const float*)d_in[3];
    const float* r_bq     = (const float*)d_in[4];
    const float* r_bk     = (const float*)d_in[5];
    const float* r_bv     = (const float*)d_in[6];
    const float* r_wo     = (const float*)d_in[7];
    const float* r_bo     = (const float*)d_in[8];
    const float* aff_w    = (const float*)d_in[9];
    const float* aff_b    = (const float*)d_in[10];
    const float* patterns = (const float*)d_in[11];
    const float* i_wq     = (const float*)d_in[12];
    const float* i_wk     = (const float*)d_in[13];
    const float* i_wv     = (const float*)d_in[14];
    const float* i_bq     = (const float*)d_in[15];
    const float* i_bk     = (const float*)d_in[16];
    const float* i_bv     = (const float*)d_in[17];
    const float* i_wo     = (const float*)d_in[18];
    const float* i_bo     = (const float*)d_in[19];
    const float* ln_g     = (const float*)d_in[20];
    const float* ln_b     = (const float*)d_in[21];
    const float* comb_w   = (const float*)d_in[22];
    const float* proj_w   = (const float*)d_in[23];

    constexpr size_t MBy = 1024 * 1024;
    char* base = (char*)d_ws;

    // region A 0-16MB: x planes -> ap planes -> { comb/proj weights (0-6) | act (8-16) }
    u16* xh   = (u16*)(base);             u16* xl   = (u16*)(base + 8 * MBy);
    u16* aph  = xh;                        u16* apl  = xl;
    u16* cbh  = (u16*)(base);             u16* cbl  = (u16*)(base + 1 * MBy);
    u16* pjh  = (u16*)(base + 2 * MBy);   u16* pjl  = (u16*)(base + 4 * MBy);
    u16* acth = (u16*)(base + 8 * MBy);   u16* actl = (u16*)(base + 12 * MBy);
    // region B 16-32MB: rq -> ctx -> pa
    u16* rqh  = (u16*)(base + 16 * MBy);  u16* rql  = (u16*)(base + 24 * MBy);
    u16* ctxh = rqh;                       u16* ctxl = rql;
    u16* pah  = rqh;                       u16* pal  = rql;
    // region C 32-48MB: rk -> iq/ik -> a2f/lnm
    u16* rkh  = (u16*)(base + 32 * MBy);  u16* rkl  = (u16*)(base + 40 * MBy);
    u16* iqh  = (u16*)(base + 32 * MBy);  u16* iql  = (u16*)(base + 36 * MBy);
    u16* ikh  = (u16*)(base + 40 * MBy);  u16* ikl  = (u16*)(base + 44 * MBy);
    u16* a2fh = iqh;                       u16* a2fl = iql;
    u16* lnmh = ikh;                       u16* lnml = ikl;
    // region D 48-64MB: rvt -> ivt / a2p
    u16* rvth = (u16*)(base + 48 * MBy);  u16* rvtl = (u16*)(base + 56 * MBy);
    u16* ivth = (u16*)(base + 48 * MBy);  u16* ivtl = (u16*)(base + 52 * MBy);
    u16* a2ph = (u16*)(base + 56 * MBy);  u16* a2pl = (u16*)(base + 60 * MBy);
    // region E 64-76MB: weights. wave1: router QKV (12MB). wave2a after QKV:
    u16* wqkvh  = (u16*)(base + 64 * MBy); u16* wqkvl = (u16*)(base + 70 * MBy);
    u16* woh    = (u16*)(base + 64 * MBy); u16* wol   = (u16*)(base + 66 * MBy);
    u16* apbh   = (u16*)(base + 68 * MBy); u16* apbl  = (u16*)(base + 70 * MBy);
    u16* iwqkvh = (u16*)(base + 72 * MBy);
    u16* iwqkvl = (u16*)(base + 72 * MBy + 1572864);   // +1.5MB
    u16* iwoh   = (u16*)(base + 75 * MBy);
    u16* iwol   = (u16*)(base + 75 * MBy + 524288);    // +0.5MB
    // region F 76MB+: smalls
    float* partial = (float*)(base + 76 * MBy);                 // 128 KB max
    float* maskI   = (float*)(base + 76 * MBy + 262144);
    float* maskP   = maskI + 2048;
    float* rbias   = maskP + 4096;        // 3072 f32
    float* ibias   = rbias + 3072;        // 1536 f32
    float* apbias  = ibias + 1536;        // 1024 f32

    const float scale = 0.08838834764831843f;  // 1/sqrt(128)
    dim3 blk(256);

    // --- biases + wave-1 packs (x, router QKV weights) in 2 dispatches ---
    concat_bias<<<dim3(1), dim3(1024), 0, stream>>>(r_bq, r_bk, r_bv,
        i_bq, i_bk, i_bv, aff_b, rbias, ibias, apbias);
    {
        PArgs a{};
        a.g[0] = {x,    xh,              xl,              1048576, 0};
        a.g[1] = {r_wq, wqkvh,           wqkvl,           262144,  0};
        a.g[2] = {r_wk, wqkvh + 1048576, wqkvl + 1048576, 262144,  0};
        a.g[3] = {r_wv, wqkvh + 2097152, wqkvl + 2097152, 262144,  0};
        pack_many<<<dim3(4096, 4), blk, 0, stream>>>(a);
    }

    // --- router fused QKV GEMM (Q,K planes + V transposed planes) ---
    gemm_planes<128, true, false, 3><<<dim3(24, 32), blk, 0, stream>>>(
        xh, xl, wqkvh, wqkvl, rbias, nullptr,
        rqh, rql, rkh, rkl, rvth, rvtl, 4096, 3072, 1024, 8, 1024);

    // --- wave-2a packs (wqkv dead): wo, aff|patterns CONCAT, i_w* CONCAT ---
    {
        PArgs a{};
        a.g[0] = {r_wo,     woh,             wol,             262144, 0};
        a.g[1] = {aff_w,    apbh,            apbl,            131072, 0};
        a.g[2] = {patterns, apbh + 524288,   apbl + 524288,   131072, 0};
        a.g[3] = {i_wq,     iwqkvh,          iwqkvl,          65536,  0};
        a.g[4] = {i_wk,     iwqkvh + 262144, iwqkvl + 262144, 65536,  0};
        a.g[5] = {i_wv,     iwqkvh + 524288, iwqkvl + 524288, 65536,  0};
        a.g[6] = {i_wo,     iwoh,            iwol,            65536,  0};
        pack_many<<<dim3(1024, 7), blk, 0, stream>>>(a);
    }

    attn_planes<4><<<dim3(16, 32), dim3(256), 0, stream>>>(
        rqh, rql, rkh, rkl, rvth, rvtl, aph, apl, 1024, 1024, 8, scale);
    gemm_planes<128, true, false, 1><<<dim3(8, 32), blk, 0, stream>>>(
        aph, apl, woh, wol, r_bo, nullptr,
        ctxh, ctxl, nullptr, nullptr, nullptr, nullptr, 4096, 1024, 1024, 0, 0);

    // --- fused affinity-max partials | gelu(patterns) act planes ---
    gemm_planes<128, true, false, 4><<<dim3(8, 32), blk, 0, stream>>>(
        ctxh, ctxl, apbh, apbl, apbias, partial,
        acth, actl, nullptr, nullptr, nullptr, nullptr, 4096, 1024, 1024, 0, 512);
    topk_rank<512, 256, 0><<<dim3(4), dim3(512), 0, stream>>>(partial, maskI);

    // --- wave-2b packs (region A front free after wo GEMM): comb, proj^T ---
    pack_f32<<<512, blk, 0, stream>>>(comb_w, cbh, cbl, 131072);
    packT64<<<dim3(16, 16), blk, 0, stream>>>(proj_w, pjh, pjl, 1024, 1024);

    // --- InputNeurons ---
    gemm_planes<128, true, false, 3><<<dim3(12, 32), blk, 0, stream>>>(
        acth, actl, iwqkvh, iwqkvl, ibias, nullptr,
        iqh, iql, ikh, ikl, ivth, ivtl, 4096, 1536, 512, 4, 512);
    attn_planes<2><<<dim3(32, 16), dim3(128), 0, stream>>>(
        iqh, iql, ikh, ikl, ivth, ivtl, a2ph, a2pl, 1024, 512, 4, scale);
    gemm_planes<64, true, false, 1><<<dim3(8, 32), blk, 0, stream>>>(
        a2ph, a2pl, iwoh, iwol, i_bo, nullptr,
        a2fh, a2fl, nullptr, nullptr, nullptr, nullptr, 4096, 512, 512, 0, 0);
    ln_mask_planes<<<dim3(4096), blk, 0, stream>>>(acth, actl, a2fh, a2fl,
                                                   ln_g, ln_b, maskI, lnmh, lnml);

    // --- ProcessNeurons: comb GEMM + fused column-sum partials ---
    gemm_planes<128, true, true, 5><<<dim3(8, 32), blk, 0, stream>>>(
        lnmh, lnml, cbh, cbl, nullptr, partial,
        pah, pal, nullptr, nullptr, nullptr, nullptr, 4096, 1024, 512, 0, 0);
    topk_rank<1024, 512, 1><<<dim3(4), dim3(1024), 0, stream>>>(partial, maskP);
    mask_rows<<<4096, blk, 0, stream>>>(pah, maskP);

    // --- final projection (hi planes only, 1 MFMA) ---
    gemm_planes<128, false, false, 0><<<dim3(8, 32), blk, 0, stream>>>(
        pah, nullptr, pjh, nullptr, nullptr, (float*)d_out,
        nullptr, nullptr, nullptr, nullptr, nullptr, nullptr, 4096, 1024, 1024, 0, 0);
}

// Round 12
// 517.736 us; speedup vs baseline: 1.0127x; 1.0127x over previous
//
#include <hip/hip_runtime.h>
#include <math.h>

#define DEVI static __device__ __forceinline__

typedef __attribute__((ext_vector_type(8))) short short8;
typedef __attribute__((ext_vector_type(4))) float f32x4;
typedef unsigned short u16;

DEVI float gelu_f(float x) {
    return 0.5f * x * (1.0f + erff(x * 0.7071067811865475f));
}
DEVI u16 f2bf(float f) {
    unsigned u = __builtin_bit_cast(unsigned, f);
    return (u16)((u + 0x7fffu + ((u >> 16) & 1u)) >> 16);
}
DEVI float bf2f(u16 b) {
    unsigned u = ((unsigned)b) << 16;
    return __builtin_bit_cast(float, u);
}
DEVI void split_bf(float v, u16& h, u16& l) {
    h = f2bf(v);
    l = f2bf(v - bf2f(h));
}

// ---------------------------------------------------------------------------
// Plane GEMM (R6/R10-proven inner loop — no cross-barrier register prefetch:
// lambda-captured prefetch arrays spill to scratch, rule #20 / R9 post-mortem).
// C[M,N] = act((Ah+Al)[M,K] @ (Bh+Bl)[N,K]^T + bias); SPLIT = 3-MFMA product.
// Block 256 thr / 4 waves, tile 128xBN, BK=64, LDS rows padded to 72 shorts.
// OMODE: 0 f32 out; 1 planes out;
//        3 fused QKV (Q planes | K planes | V transposed planes) — B operand
//          MUST be the CONCATENATED [2*partN + HH*128][K] weight planes;
//        4 col<partN: column-MAX partials -> Cf[32][partN];
//          col>=partN: gelu planes -> O1 (stride partN);
//        5 planes out (gelu) + column-SUM partials -> Cf[32][N].
// Partial reductions are fixed-order (deterministic).
// ---------------------------------------------------------------------------
template<int BN, bool SPLIT, bool DO_GELU, int OMODE>
__global__ __launch_bounds__(256, 2)
void gemm_planes(const u16* __restrict__ Agh, const u16* __restrict__ Agl,
                 const u16* __restrict__ Bgh, const u16* __restrict__ Bgl,
                 const float* __restrict__ bias, float* __restrict__ Cf,
                 u16* __restrict__ O1h, u16* __restrict__ O1l,
                 u16* __restrict__ O2h, u16* __restrict__ O2l,
                 u16* __restrict__ O3h, u16* __restrict__ O3l,
                 int M, int N, int K, int HH, int partN)
{
    constexpr int BM = 128, BK = 64, PK = 72;
    constexpr int NPL = SPLIT ? 2 : 1;
    constexpr int MF  = (BN == 128) ? 4 : 2;
    constexpr int NB  = BN / 32;
    __shared__ __align__(16) u16 As[NPL][BM * PK];
    __shared__ __align__(16) u16 Bs[NPL][BN * PK];
    const int t = threadIdx.x, w = t >> 6, l = t & 63;
    const int lr = l & 15, lg = l >> 4;
    const int m0 = blockIdx.y * BM, n0 = blockIdx.x * BN;
    const int moff = (BN == 128) ? (w >> 1) * 64 : w * 32;
    const int noff = (BN == 128) ? (w & 1) * 64 : 0;
    const int srow = t >> 3, sslot = t & 7;

    f32x4 acc[MF][4];
    #pragma unroll
    for (int i = 0; i < MF; ++i)
        #pragma unroll
        for (int j = 0; j < 4; ++j) acc[i][j] = 0.0f;

    for (int k0 = 0; k0 < K; k0 += BK) {
        __syncthreads();   // previous tile fully consumed
        #pragma unroll
        for (int p = 0; p < 4; ++p) {
            int row = p * 32 + srow;
            size_t g = (size_t)(m0 + row) * K + k0 + sslot * 8;
            *(uint4*)&As[0][row * PK + sslot * 8] = *(const uint4*)&Agh[g];
            if constexpr (SPLIT)
                *(uint4*)&As[1][row * PK + sslot * 8] = *(const uint4*)&Agl[g];
        }
        #pragma unroll
        for (int p = 0; p < NB; ++p) {
            int row = p * 32 + srow;
            size_t g = (size_t)(n0 + row) * K + k0 + sslot * 8;
            *(uint4*)&Bs[0][row * PK + sslot * 8] = *(const uint4*)&Bgh[g];
            if constexpr (SPLIT)
                *(uint4*)&Bs[1][row * PK + sslot * 8] = *(const uint4*)&Bgl[g];
        }
        __syncthreads();
        #pragma unroll
        for (int ks = 0; ks < 2; ++ks) {
            short8 af[MF][NPL], bfr[4][NPL];
            #pragma unroll
            for (int mf = 0; mf < MF; ++mf) {
                int a = (moff + mf * 16 + lr) * PK + ks * 32 + lg * 8;
                af[mf][0] = *(const short8*)&As[0][a];
                if constexpr (SPLIT) af[mf][1] = *(const short8*)&As[1][a];
            }
            #pragma unroll
            for (int nf = 0; nf < 4; ++nf) {
                int a = (noff + nf * 16 + lr) * PK + ks * 32 + lg * 8;
                bfr[nf][0] = *(const short8*)&Bs[0][a];
                if constexpr (SPLIT) bfr[nf][1] = *(const short8*)&Bs[1][a];
            }
            #pragma unroll
            for (int mf = 0; mf < MF; ++mf)
                #pragma unroll
                for (int nf = 0; nf < 4; ++nf) {
                    acc[mf][nf] = __builtin_amdgcn_mfma_f32_16x16x32_bf16(
                        af[mf][0], bfr[nf][0], acc[mf][nf], 0, 0, 0);
                    if constexpr (SPLIT) {
                        acc[mf][nf] = __builtin_amdgcn_mfma_f32_16x16x32_bf16(
                            af[mf][0], bfr[nf][1], acc[mf][nf], 0, 0, 0);
                        acc[mf][nf] = __builtin_amdgcn_mfma_f32_16x16x32_bf16(
                            af[mf][1], bfr[nf][0], acc[mf][nf], 0, 0, 0);
                    }
                }
        }
    }

    // ---- epilogue: C row = lg*4+r, col = lr within each 16x16 subtile ----
    float colred[4];
    if constexpr (OMODE == 4) {
        colred[0] = colred[1] = colred[2] = colred[3] = -3.402823466e38f;
    } else if constexpr (OMODE == 5) {
        colred[0] = colred[1] = colred[2] = colred[3] = 0.0f;
    }
    #pragma unroll
    for (int mf = 0; mf < MF; ++mf)
        #pragma unroll
        for (int nf = 0; nf < 4; ++nf) {
            int col  = n0 + noff + nf * 16 + lr;
            int mrow = m0 + moff + mf * 16 + lg * 4;
            float bv = bias ? bias[col] : 0.0f;
            float ov[4];
            #pragma unroll
            for (int r = 0; r < 4; ++r) ov[r] = acc[mf][nf][r] + bv;
            if constexpr (OMODE == 0) {
                #pragma unroll
                for (int r = 0; r < 4; ++r) {
                    float o = ov[r];
                    if constexpr (DO_GELU) o = gelu_f(o);
                    Cf[(size_t)(mrow + r) * N + col] = o;
                }
            } else if constexpr (OMODE == 1) {
                #pragma unroll
                for (int r = 0; r < 4; ++r) {
                    float o = ov[r];
                    if constexpr (DO_GELU) o = gelu_f(o);
                    u16 hb, lb; split_bf(o, hb, lb);
                    O1h[(size_t)(mrow + r) * N + col] = hb;
                    O1l[(size_t)(mrow + r) * N + col] = lb;
                }
            } else if constexpr (OMODE == 3) {
                if (col < partN) {
                    #pragma unroll
                    for (int r = 0; r < 4; ++r) {
                        u16 hb, lb; split_bf(ov[r], hb, lb);
                        O1h[(size_t)(mrow + r) * partN + col] = hb;
                        O1l[(size_t)(mrow + r) * partN + col] = lb;
                    }
                } else if (col < 2 * partN) {
                    int c2 = col - partN;
                    #pragma unroll
                    for (int r = 0; r < 4; ++r) {
                        u16 hb, lb; split_bf(ov[r], hb, lb);
                        O2h[(size_t)(mrow + r) * partN + c2] = hb;
                        O2l[(size_t)(mrow + r) * partN + c2] = lb;
                    }
                } else {
                    int c2 = col - 2 * partN;
                    int hh = c2 >> 7, dd = c2 & 127;
                    int bb = mrow >> 10, s0 = mrow & 1023;
                    size_t idx = ((size_t)(bb * HH + hh) * 128 + dd) * 1024 + s0;
                    ushort4 oh, ol;
                    #pragma unroll
                    for (int r = 0; r < 4; ++r) {
                        u16 hb, lb; split_bf(ov[r], hb, lb);
                        ((u16*)&oh)[r] = hb; ((u16*)&ol)[r] = lb;
                    }
                    *(ushort4*)&O3h[idx] = oh;
                    *(ushort4*)&O3l[idx] = ol;
                }
            } else if constexpr (OMODE == 4) {
                if (n0 < partN) {
                    #pragma unroll
                    for (int r = 0; r < 4; ++r)
                        colred[nf] = fmaxf(colred[nf], ov[r]);
                } else {
                    int c2 = col - partN;
                    #pragma unroll
                    for (int r = 0; r < 4; ++r) {
                        float o = gelu_f(ov[r]);
                        u16 hb, lb; split_bf(o, hb, lb);
                        O1h[(size_t)(mrow + r) * partN + c2] = hb;
                        O1l[(size_t)(mrow + r) * partN + c2] = lb;
                    }
                }
            } else if constexpr (OMODE == 5) {
                #pragma unroll
                for (int r = 0; r < 4; ++r) {
                    float o = gelu_f(ov[r]);
                    colred[nf] += o;
                    u16 hb, lb; split_bf(o, hb, lb);
                    O1h[(size_t)(mrow + r) * N + col] = hb;
                    O1l[(size_t)(mrow + r) * N + col] = lb;
                }
            }
        }
    // ---- fixed-order per-block column reduction (deterministic) ----
    if constexpr (OMODE == 4 || OMODE == 5) {
        bool doRed = (OMODE == 5) || (n0 < partN);
        if (doRed) {
            __syncthreads();
            float* sred = (float*)&As[0][0];   // 4 KB scratch, tile dead
            #pragma unroll
            for (int nf = 0; nf < 4; ++nf) sred[t * 4 + nf] = colred[nf];
            __syncthreads();
            if (t < 128) {
                int cl = t, lrr = cl & 15, nff = (cl & 63) >> 4, wb = cl >> 6;
                float a = (OMODE == 4) ? -3.402823466e38f : 0.0f;
                #pragma unroll
                for (int k2 = 0; k2 < 2; ++k2)
                    #pragma unroll
                    for (int l2 = 0; l2 < 4; ++l2) {
                        float v = sred[(((wb + 2 * k2) * 64) + l2 * 16 + lrr) * 4 + nff];
                        if constexpr (OMODE == 4) a = fmaxf(a, v); else a += v;
                    }
                int stride = (OMODE == 4) ? partN : N;
                Cf[(size_t)blockIdx.y * stride + n0 + cl] = a;
            }
        }
    }
}

// ---------------------------------------------------------------------------
// Plane flash attention (R4/R10-proven, NW=4 — R11's NW=2 doubled staging
// traffic and regressed; staging-bound, not barrier-bound) + XCD swizzle (T1).
// ---------------------------------------------------------------------------
__global__ __launch_bounds__(256, 3)
void attn_planes(const u16* __restrict__ Qh, const u16* __restrict__ Ql,
                 const u16* __restrict__ Kh, const u16* __restrict__ Kl,
                 const u16* __restrict__ Vh, const u16* __restrict__ Vl,
                 u16* __restrict__ Oh, u16* __restrict__ Ol,
                 int S, int Dm, int H, float scale)
{
    __shared__ __align__(16) u16 KsL[2][32 * 136];
    __shared__ __align__(16) u16 VsL[2][128 * 40];
    __shared__ __align__(16) u16 PsL[2][4 * 16 * 40];
    const int t = threadIdx.x, w = t >> 6, l = t & 63;
    const int lr = l & 15, lg = l >> 4;
    const int nqt = gridDim.x;
    const int nwg = nqt * gridDim.y;
    const int fid = blockIdx.y * nqt + blockIdx.x;
    const int nid = (fid & 7) * (nwg >> 3) + (fid >> 3);
    const int bh = nid / nqt, qt = nid - bh * nqt;
    const int b = bh / H, h = bh - b * H;
    const int q0 = qt * 64 + w * 16;
    const size_t qkbase = (size_t)(b * S) * Dm + h * 128;
    const size_t vbase  = (size_t)(b * H + h) * 128 * 1024;

    short8 qhf[4], qlf[4];
    #pragma unroll
    for (int ks = 0; ks < 4; ++ks) {
        size_t g = qkbase + (size_t)(q0 + lr) * Dm + ks * 32 + lg * 8;
        qhf[ks] = *(const short8*)&Qh[g];
        qlf[ks] = *(const short8*)&Ql[g];
    }
    f32x4 accO[8];
    #pragma unroll
    for (int i = 0; i < 8; ++i) accO[i] = 0.0f;
    float ls = 0.0f;
    const int pw = w * 640;

    for (int c0 = 0; c0 < S; c0 += 32) {
        __syncthreads();
        #pragma unroll
        for (int p = 0; p < 2; ++p) {
            int key = p * 16 + (t >> 4);
            int slot = t & 15;
            size_t g = qkbase + (size_t)(c0 + key) * Dm + slot * 8;
            *(uint4*)&KsL[0][key * 136 + slot * 8] = *(const uint4*)&Kh[g];
            *(uint4*)&KsL[1][key * 136 + slot * 8] = *(const uint4*)&Kl[g];
        }
        #pragma unroll
        for (int p = 0; p < 2; ++p) {
            int d = p * 64 + (t >> 2);
            int ksl = t & 3;
            size_t g = vbase + (size_t)d * 1024 + c0 + ksl * 8;
            *(uint4*)&VsL[0][d * 40 + ksl * 8] = *(const uint4*)&Vh[g];
            *(uint4*)&VsL[1][d * 40 + ksl * 8] = *(const uint4*)&Vl[g];
        }
        __syncthreads();
        f32x4 sac[2];
        sac[0] = 0.0f; sac[1] = 0.0f;
        #pragma unroll
        for (int mt = 0; mt < 2; ++mt)
            #pragma unroll
            for (int ks = 0; ks < 4; ++ks) {
                int a = (mt * 16 + lr) * 136 + ks * 32 + lg * 8;
                short8 khf = *(const short8*)&KsL[0][a];
                short8 klf = *(const short8*)&KsL[1][a];
                sac[mt] = __builtin_amdgcn_mfma_f32_16x16x32_bf16(khf, qhf[ks], sac[mt], 0, 0, 0);
                sac[mt] = __builtin_amdgcn_mfma_f32_16x16x32_bf16(khf, qlf[ks], sac[mt], 0, 0, 0);
                sac[mt] = __builtin_amdgcn_mfma_f32_16x16x32_bf16(klf, qhf[ks], sac[mt], 0, 0, 0);
            }
        #pragma unroll
        for (int mt = 0; mt < 2; ++mt)
            #pragma unroll
            for (int rr = 0; rr < 4; ++rr) {
                float p = __expf(sac[mt][rr] * scale);
                ls += p;
                int key = mt * 16 + lg * 4 + rr;
                u16 hb, lb; split_bf(p, hb, lb);
                PsL[0][pw + lr * 40 + key] = hb;
                PsL[1][pw + lr * 40 + key] = lb;
            }
        short8 pah = *(const short8*)&PsL[0][pw + lr * 40 + lg * 8];
        short8 pal = *(const short8*)&PsL[1][pw + lr * 40 + lg * 8];
        #pragma unroll
        for (int nt = 0; nt < 8; ++nt) {
            int a = (nt * 16 + lr) * 40 + lg * 8;
            short8 vhf = *(const short8*)&VsL[0][a];
            short8 vlf = *(const short8*)&VsL[1][a];
            accO[nt] = __builtin_amdgcn_mfma_f32_16x16x32_bf16(pah, vhf, accO[nt], 0, 0, 0);
            accO[nt] = __builtin_amdgcn_mfma_f32_16x16x32_bf16(pah, vlf, accO[nt], 0, 0, 0);
            accO[nt] = __builtin_amdgcn_mfma_f32_16x16x32_bf16(pal, vhf, accO[nt], 0, 0, 0);
        }
    }
    float lt = ls + __shfl_xor(ls, 16, 64);
    lt += __shfl_xor(lt, 32, 64);
    #pragma unroll
    for (int rr = 0; rr < 4; ++rr) {
        float inv = 1.0f / __shfl(lt, lg * 4 + rr, 64);
        size_t rowoff = qkbase + (size_t)(q0 + lg * 4 + rr) * Dm;
        #pragma unroll
        for (int nt = 0; nt < 8; ++nt) {
            float o = accO[nt][rr] * inv;
            u16 hb, lb; split_bf(o, hb, lb);
            Oh[rowoff + nt * 16 + lr] = hb;
            Ol[rowoff + nt * 16 + lr] = lb;
        }
    }
}

// ---------------------------------------------------------------------------
// Multi-segment packer: fp32 -> bf16 hi/lo planes. n4 = count of float4s.
// ---------------------------------------------------------------------------
struct PSeg { const float* s; u16* h; u16* l; int n4; int pad; };
struct PArgs { PSeg g[8]; };

__global__ __launch_bounds__(256)
void pack_many(PArgs a)
{
    PSeg sg = a.g[blockIdx.y];
    int i = blockIdx.x * 256 + threadIdx.x;
    if (i >= sg.n4) return;
    float4 v = *(const float4*)&sg.s[i * 4];
    ushort4 hv, lv;
    split_bf(v.x, hv.x, lv.x);
    split_bf(v.y, hv.y, lv.y);
    split_bf(v.z, hv.z, lv.z);
    split_bf(v.w, hv.w, lv.w);
    *(ushort4*)&sg.h[i * 4] = hv;
    *(ushort4*)&sg.l[i * 4] = lv;
}

__global__ __launch_bounds__(256)
void pack_f32(const float* __restrict__ src, u16* __restrict__ dh,
              u16* __restrict__ dl, int n4)
{
    int i = blockIdx.x * 256 + threadIdx.x;
    if (i >= n4) return;
    float4 v = *(const float4*)&src[i * 4];
    ushort4 hv, lv;
    split_bf(v.x, hv.x, lv.x);
    split_bf(v.y, hv.y, lv.y);
    split_bf(v.z, hv.z, lv.z);
    split_bf(v.w, hv.w, lv.w);
    *(ushort4*)&dh[i * 4] = hv;
    *(ushort4*)&dl[i * 4] = lv;
}

__global__ __launch_bounds__(256)
void packT64(const float* __restrict__ src, u16* __restrict__ dh,
             u16* __restrict__ dl, int R, int C)
{
    __shared__ float tile[64][65];
    int r0 = blockIdx.y * 64, c0 = blockIdx.x * 64;
    int t = threadIdx.x;
    #pragma unroll
    for (int i = 0; i < 16; ++i) {
        int idx = i * 256 + t, rr = idx >> 6, cc = idx & 63;
        tile[rr][cc] = src[(size_t)(r0 + rr) * C + c0 + cc];
    }
    __syncthreads();
    #pragma unroll
    for (int i = 0; i < 16; ++i) {
        int idx = i * 256 + t, rr = idx >> 6, cc = idx & 63;
        float v = tile[cc][rr];
        u16 hb, lb; split_bf(v, hb, lb);
        size_t o = (size_t)(c0 + rr) * R + r0 + cc;
        dh[o] = hb; dl[o] = lb;
    }
}

// concat biases: rbias[3072], ibias[1536], apbias[1024] (aff_b | zeros)
__global__ __launch_bounds__(1024)
void concat_bias(const float* rq, const float* rk, const float* rv,
                 const float* iq, const float* ik, const float* iv,
                 const float* ab, float* rb, float* ib, float* apb)
{
    int t = threadIdx.x;
    rb[t]        = rq[t];
    rb[1024 + t] = rk[t];
    rb[2048 + t] = rv[t];
    apb[t] = (t < 512) ? ab[t] : 0.0f;
    if (t < 512) {
        ib[t]        = iq[t];
        ib[512 + t]  = ik[t];
        ib[1024 + t] = iv[t];
    }
}

__global__ __launch_bounds__(256)
void mask_rows(u16* __restrict__ ph, const float* __restrict__ mask)
{
    int i = blockIdx.x * 256 + threadIdx.x;
    int i4 = i * 4;
    int bb = i4 >> 20;
    int col = i4 & 1023;
    ushort4 v = *(ushort4*)&ph[i4];
    float4 m = *(const float4*)&mask[bb * 1024 + col];
    if (m.x == 0.f) v.x = 0;
    if (m.y == 0.f) v.y = 0;
    if (m.z == 0.f) v.z = 0;
    if (m.w == 0.f) v.w = 0;
    *(ushort4*)&ph[i4] = v;
}

// ---------------------------------------------------------------------------
// Fused partial-reduce (8 row-blocks, fixed order) + top-K mask via RANK
// COUNTING: rank(i) = #{v_j > v_i} + #{v_j == v_i, j < i}; mask = rank < K.
// Identical tie semantics to jax.lax.top_k (val desc, idx asc).
// ---------------------------------------------------------------------------
template<int N, int KSEL, int OP>
__global__ __launch_bounds__(1024)
void topk_rank(const float* __restrict__ P, float* __restrict__ mask)
{
    __shared__ float v[N];
    int t = threadIdx.x, b = blockIdx.x;
    float a = (OP == 0) ? -3.402823466e38f : 0.0f;
    #pragma unroll
    for (int r = 0; r < 8; ++r) {
        float x = P[(size_t)(b * 8 + r) * N + t];
        if (OP == 0) a = fmaxf(a, x); else a += x;
    }
    v[t] = a;
    __syncthreads();
    int rank = 0;
    for (int j = 0; j < N; ++j) {
        float vj = v[j];                    // LDS broadcast (conflict-free)
        rank += (vj > a) || (vj == a && j < t);
    }
    mask[b * N + t] = (rank < KSEL) ? 1.0f : 0.0f;
}

__global__ __launch_bounds__(256)
void ln_mask_planes(const u16* __restrict__ Xh, const u16* __restrict__ Xl,
                    const u16* __restrict__ Rh, const u16* __restrict__ Rl,
                    const float* __restrict__ gam, const float* __restrict__ bet,
                    const float* __restrict__ mask,
                    u16* __restrict__ Yh, u16* __restrict__ Yl)
{
    int row = blockIdx.x, bb = row >> 10, t = threadIdx.x;
    size_t base = (size_t)row * 512;
    float a1 = bf2f(Xh[base + t]) + bf2f(Xl[base + t])
             + bf2f(Rh[base + t]) + bf2f(Rl[base + t]);
    float a2 = bf2f(Xh[base + t + 256]) + bf2f(Xl[base + t + 256])
             + bf2f(Rh[base + t + 256]) + bf2f(Rl[base + t + 256]);
    float s  = a1 + a2;
    float sq = a1 * a1 + a2 * a2;
    #pragma unroll
    for (int off = 32; off > 0; off >>= 1) {
        s  += __shfl_down(s, off, 64);
        sq += __shfl_down(sq, off, 64);
    }
    __shared__ float red[8];
    int wid = t >> 6, lane = t & 63;
    if (lane == 0) { red[wid] = s; red[wid + 4] = sq; }
    __syncthreads();
    if (t == 0) {
        float st  = red[0] + red[1] + red[2] + red[3];
        float sqt = red[4] + red[5] + red[6] + red[7];
        float mu  = st / 512.0f;
        float var = sqt / 512.0f - mu * mu;
        red[0] = mu;
        red[1] = rsqrtf(var + 1e-5f);
    }
    __syncthreads();
    float mu = red[0], rstd = red[1];
    float y1 = ((a1 - mu) * rstd * gam[t] + bet[t]) * mask[bb * 512 + t];
    float y2 = ((a2 - mu) * rstd * gam[t + 256] + bet[t + 256]) * mask[bb * 512 + t + 256];
    u16 hb, lb;
    split_bf(y1, hb, lb); Yh[base + t] = hb;       Yl[base + t] = lb;
    split_bf(y2, hb, lb); Yh[base + t + 256] = hb; Yl[base + t + 256] = lb;
}

// ---------------------------------------------------------------------------
extern "C" void kernel_launch(void* const* d_in, const int* in_sizes, int n_in,
                              void* d_out, int out_size, void* d_ws, size_t ws_size,
                              hipStream_t stream)
{
    (void)in_sizes; (void)n_in; (void)out_size; (void)ws_size;
    const float* x        = (const float*)d_in[0];
    const float* r_wq     = (const float*)d_in[1];
    const float* r_wk     = (const float*)d_in[2];
    const float* r_wv     = (const float*)d_in[3];
    const float* r_bq     = (const float*)d_in[4];
    const float* r_bk     = (const float*)d_in[5];
    const float* r_bv     = (const float*)d_in[6];
    const float* r_wo     = (const float*)d_in[7];
    const float* r_bo     = (const float*)d_in[8];
    const float* aff_w    = (const float*)d_in[9];
    const float* aff_b    = (const float*)d_in[10];
    const float* patterns = (const float*)d_in[11];
    const float* i_wq     = (const float*)d_in[12];
    const float* i_wk     = (const float*)d_in[13];
    const float* i_wv     = (const float*)d_in[14];
    const float* i_bq     = (const float*)d_in[15];
    const float* i_bk     = (const float*)d_in[16];
    const float* i_bv     = (const float*)d_in[17];
    const float* i_wo     = (const float*)d_in[18];
    const float* i_bo     = (const float*)d_in[19];
    const float* ln_g     = (const float*)d_in[20];
    const float* ln_b     = (const float*)d_in[21];
    const float* comb_w   = (const float*)d_in[22];
    const float* proj_w   = (const float*)d_in[23];

    constexpr size_t MBy = 1024 * 1024;
    char* base = (char*)d_ws;

    // region A 0-16MB: x planes -> ap planes -> { comb/proj weights (0-6) | act (8-16) }
    u16* xh   = (u16*)(base);             u16* xl   = (u16*)(base + 8 * MBy);
    u16* aph  = xh;                        u16* apl  = xl;
    u16* cbh  = (u16*)(base);             u16* cbl  = (u16*)(base + 1 * MBy);
    u16* pjh  = (u16*)(base + 2 * MBy);   u16* pjl  = (u16*)(base + 4 * MBy);
    u16* acth = (u16*)(base + 8 * MBy);   u16* actl = (u16*)(base + 12 * MBy);
    // region B 16-32MB: rq -> ctx -> pa
    u16* rqh  = (u16*)(base + 16 * MBy);  u16* rql  = (u16*)(base + 24 * MBy);
    u16* ctxh = rqh;                       u16* ctxl = rql;
    u16* pah  = rqh;                       u16* pal  = rql;
    // region C 32-48MB: rk -> iq/ik -> a2f/lnm
    u16* rkh  = (u16*)(base + 32 * MBy);  u16* rkl  = (u16*)(base + 40 * MBy);
    u16* iqh  = (u16*)(base + 32 * MBy);  u16* iql  = (u16*)(base + 36 * MBy);
    u16* ikh  = (u16*)(base + 40 * MBy);  u16* ikl  = (u16*)(base + 44 * MBy);
    u16* a2fh = iqh;                       u16* a2fl = iql;
    u16* lnmh = ikh;                       u16* lnml = ikl;
    // region D 48-64MB: rvt -> ivt / a2p
    u16* rvth = (u16*)(base + 48 * MBy);  u16* rvtl = (u16*)(base + 56 * MBy);
    u16* ivth = (u16*)(base + 48 * MBy);  u16* ivtl = (u16*)(base + 52 * MBy);
    u16* a2ph = (u16*)(base + 56 * MBy);  u16* a2pl = (u16*)(base + 60 * MBy);
    // region E 64-76MB: weights. wave1: router QKV (12MB). wave2a after QKV:
    u16* wqkvh  = (u16*)(base + 64 * MBy); u16* wqkvl = (u16*)(base + 70 * MBy);
    u16* woh    = (u16*)(base + 64 * MBy); u16* wol   = (u16*)(base + 66 * MBy);
    u16* apbh   = (u16*)(base + 68 * MBy); u16* apbl  = (u16*)(base + 70 * MBy);
    u16* iwqkvh = (u16*)(base + 72 * MBy);
    u16* iwqkvl = (u16*)(base + 72 * MBy + 1572864);   // +1.5MB
    u16* iwoh   = (u16*)(base + 75 * MBy);
    u16* iwol   = (u16*)(base + 75 * MBy + 524288);    // +0.5MB
    // region F 76MB+: smalls
    float* partial = (float*)(base + 76 * MBy);                 // 128 KB max
    float* maskI   = (float*)(base + 76 * MBy + 262144);
    float* maskP   = maskI + 2048;
    float* rbias   = maskP + 4096;        // 3072 f32
    float* ibias   = rbias + 3072;        // 1536 f32
    float* apbias  = ibias + 1536;        // 1024 f32

    const float scale = 0.08838834764831843f;  // 1/sqrt(128)
    dim3 blk(256);

    // --- biases + wave-1 packs (x, router QKV weights) in 2 dispatches ---
    concat_bias<<<dim3(1), dim3(1024), 0, stream>>>(r_bq, r_bk, r_bv,
        i_bq, i_bk, i_bv, aff_b, rbias, ibias, apbias);
    {
        PArgs a{};
        a.g[0] = {x,    xh,              xl,              1048576, 0};
        a.g[1] = {r_wq, wqkvh,           wqkvl,           262144,  0};
        a.g[2] = {r_wk, wqkvh + 1048576, wqkvl + 1048576, 262144,  0};
        a.g[3] = {r_wv, wqkvh + 2097152, wqkvl + 2097152, 262144,  0};
        pack_many<<<dim3(4096, 4), blk, 0, stream>>>(a);
    }

    // --- router fused QKV GEMM (Q,K planes + V transposed planes) ---
    gemm_planes<128, true, false, 3><<<dim3(24, 32), blk, 0, stream>>>(
        xh, xl, wqkvh, wqkvl, rbias, nullptr,
        rqh, rql, rkh, rkl, rvth, rvtl, 4096, 3072, 1024, 8, 1024);

    // --- wave-2a packs (wqkv dead): wo, aff|patterns CONCAT, i_w* CONCAT ---
    {
        PArgs a{};
        a.g[0] = {r_wo,     woh,             wol,             262144, 0};
        a.g[1] = {aff_w,    apbh,            apbl,            131072, 0};
        a.g[2] = {patterns, apbh + 524288,   apbl + 524288,   131072, 0};
        a.g[3] = {i_wq,     iwqkvh,          iwqkvl,          65536,  0};
        a.g[4] = {i_wk,     iwqkvh + 262144, iwqkvl + 262144, 65536,  0};
        a.g[5] = {i_wv,     iwqkvh + 524288, iwqkvl + 524288, 65536,  0};
        a.g[6] = {i_wo,     iwoh,            iwol,            65536,  0};
        pack_many<<<dim3(1024, 7), blk, 0, stream>>>(a);
    }

    attn_planes<<<dim3(16, 32), blk, 0, stream>>>(rqh, rql, rkh, rkl, rvth, rvtl,
                                                  aph, apl, 1024, 1024, 8, scale);
    gemm_planes<128, true, false, 1><<<dim3(8, 32), blk, 0, stream>>>(
        aph, apl, woh, wol, r_bo, nullptr,
        ctxh, ctxl, nullptr, nullptr, nullptr, nullptr, 4096, 1024, 1024, 0, 0);

    // --- fused affinity-max partials | gelu(patterns) act planes ---
    gemm_planes<128, true, false, 4><<<dim3(8, 32), blk, 0, stream>>>(
        ctxh, ctxl, apbh, apbl, apbias, partial,
        acth, actl, nullptr, nullptr, nullptr, nullptr, 4096, 1024, 1024, 0, 512);
    topk_rank<512, 256, 0><<<dim3(4), dim3(512), 0, stream>>>(partial, maskI);

    // --- wave-2b packs (region A front free after wo GEMM): comb, proj^T ---
    pack_f32<<<512, blk, 0, stream>>>(comb_w, cbh, cbl, 131072);
    packT64<<<dim3(16, 16), blk, 0, stream>>>(proj_w, pjh, pjl, 1024, 1024);

    // --- InputNeurons ---
    gemm_planes<128, true, false, 3><<<dim3(12, 32), blk, 0, stream>>>(
        acth, actl, iwqkvh, iwqkvl, ibias, nullptr,
        iqh, iql, ikh, ikl, ivth, ivtl, 4096, 1536, 512, 4, 512);
    attn_planes<<<dim3(16, 16), blk, 0, stream>>>(iqh, iql, ikh, ikl, ivth, ivtl,
                                                  a2ph, a2pl, 1024, 512, 4, scale);
    gemm_planes<64, true, false, 1><<<dim3(8, 32), blk, 0, stream>>>(
        a2ph, a2pl, iwoh, iwol, i_bo, nullptr,
        a2fh, a2fl, nullptr, nullptr, nullptr, nullptr, 4096, 512, 512, 0, 0);
    ln_mask_planes<<<dim3(4096), blk, 0, stream>>>(acth, actl, a2fh, a2fl,
                                                   ln_g, ln_b, maskI, lnmh, lnml);

    // --- ProcessNeurons: comb GEMM + fused column-sum partials ---
    gemm_planes<128, true, true, 5><<<dim3(8, 32), blk, 0, stream>>>(
        lnmh, lnml, cbh, cbl, nullptr, partial,
        pah, pal, nullptr, nullptr, nullptr, nullptr, 4096, 1024, 512, 0, 0);
    topk_rank<1024, 512, 1><<<dim3(4), dim3(1024), 0, stream>>>(partial, maskP);
    mask_rows<<<4096, blk, 0, stream>>>(pah, maskP);

    // --- final projection (hi planes only, 1 MFMA) ---
    gemm_planes<128, false, false, 0><<<dim3(8, 32), blk, 0, stream>>>(
        pah, nullptr, pjh, nullptr, nullptr, (float*)d_out,
        nullptr, nullptr, nullptr, nullptr, nullptr, nullptr, 4096, 1024, 1024, 0, 0);
}

// Round 13
// 488.457 us; speedup vs baseline: 1.0734x; 1.0599x over previous
//
#include <hip/hip_runtime.h>
#include <math.h>

#define DEVI static __device__ __forceinline__

typedef __attribute__((ext_vector_type(8))) short short8;
typedef __attribute__((ext_vector_type(4))) float f32x4;
typedef unsigned short u16;

DEVI float gelu_f(float x) {
    return 0.5f * x * (1.0f + erff(x * 0.7071067811865475f));
}
DEVI u16 f2bf(float f) {
    unsigned u = __builtin_bit_cast(unsigned, f);
    return (u16)((u + 0x7fffu + ((u >> 16) & 1u)) >> 16);
}
DEVI float bf2f(u16 b) {
    unsigned u = ((unsigned)b) << 16;
    return __builtin_bit_cast(float, u);
}
DEVI void split_bf(float v, u16& h, u16& l) {
    h = f2bf(v);
    l = f2bf(v - bf2f(h));
}

// ---------------------------------------------------------------------------
// Plane GEMM (R6/R10-proven inner loop — no cross-barrier register prefetch:
// lambda-captured prefetch arrays spill to scratch, rule #20 / R9 post-mortem).
// C[M,N] = act((Ah+Al)[M,K] @ (Bh+Bl)[N,K]^T + bias); SPLIT = 3-MFMA product.
// Block 256 thr / 4 waves, tile 128xBN, BK=64, LDS rows padded to 72 shorts.
// OMODE: 0 f32 out; 1 planes out;
//        3 fused QKV (Q planes | K planes | V transposed planes) — B operand
//          MUST be the CONCATENATED [2*partN + HH*128][K] weight planes;
//        4 col<partN: column-MAX partials -> Cf[32][partN];
//          col>=partN: gelu planes -> O1 (stride partN);
//        5 planes out (gelu) + column-SUM partials -> Cf[32][N].
// Partial reductions are fixed-order (deterministic).
// ---------------------------------------------------------------------------
template<int BN, bool SPLIT, bool DO_GELU, int OMODE>
__global__ __launch_bounds__(256, 2)
void gemm_planes(const u16* __restrict__ Agh, const u16* __restrict__ Agl,
                 const u16* __restrict__ Bgh, const u16* __restrict__ Bgl,
                 const float* __restrict__ bias, float* __restrict__ Cf,
                 u16* __restrict__ O1h, u16* __restrict__ O1l,
                 u16* __restrict__ O2h, u16* __restrict__ O2l,
                 u16* __restrict__ O3h, u16* __restrict__ O3l,
                 int M, int N, int K, int HH, int partN)
{
    constexpr int BM = 128, BK = 64, PK = 72;
    constexpr int NPL = SPLIT ? 2 : 1;
    constexpr int MF  = (BN == 128) ? 4 : 2;
    constexpr int NB  = BN / 32;
    __shared__ __align__(16) u16 As[NPL][BM * PK];
    __shared__ __align__(16) u16 Bs[NPL][BN * PK];
    const int t = threadIdx.x, w = t >> 6, l = t & 63;
    const int lr = l & 15, lg = l >> 4;
    const int m0 = blockIdx.y * BM, n0 = blockIdx.x * BN;
    const int moff = (BN == 128) ? (w >> 1) * 64 : w * 32;
    const int noff = (BN == 128) ? (w & 1) * 64 : 0;
    const int srow = t >> 3, sslot = t & 7;

    f32x4 acc[MF][4];
    #pragma unroll
    for (int i = 0; i < MF; ++i)
        #pragma unroll
        for (int j = 0; j < 4; ++j) acc[i][j] = 0.0f;

    for (int k0 = 0; k0 < K; k0 += BK) {
        __syncthreads();   // previous tile fully consumed
        #pragma unroll
        for (int p = 0; p < 4; ++p) {
            int row = p * 32 + srow;
            size_t g = (size_t)(m0 + row) * K + k0 + sslot * 8;
            *(uint4*)&As[0][row * PK + sslot * 8] = *(const uint4*)&Agh[g];
            if constexpr (SPLIT)
                *(uint4*)&As[1][row * PK + sslot * 8] = *(const uint4*)&Agl[g];
        }
        #pragma unroll
        for (int p = 0; p < NB; ++p) {
            int row = p * 32 + srow;
            size_t g = (size_t)(n0 + row) * K + k0 + sslot * 8;
            *(uint4*)&Bs[0][row * PK + sslot * 8] = *(const uint4*)&Bgh[g];
            if constexpr (SPLIT)
                *(uint4*)&Bs[1][row * PK + sslot * 8] = *(const uint4*)&Bgl[g];
        }
        __syncthreads();
        #pragma unroll
        for (int ks = 0; ks < 2; ++ks) {
            short8 af[MF][NPL], bfr[4][NPL];
            #pragma unroll
            for (int mf = 0; mf < MF; ++mf) {
                int a = (moff + mf * 16 + lr) * PK + ks * 32 + lg * 8;
                af[mf][0] = *(const short8*)&As[0][a];
                if constexpr (SPLIT) af[mf][1] = *(const short8*)&As[1][a];
            }
            #pragma unroll
            for (int nf = 0; nf < 4; ++nf) {
                int a = (noff + nf * 16 + lr) * PK + ks * 32 + lg * 8;
                bfr[nf][0] = *(const short8*)&Bs[0][a];
                if constexpr (SPLIT) bfr[nf][1] = *(const short8*)&Bs[1][a];
            }
            #pragma unroll
            for (int mf = 0; mf < MF; ++mf)
                #pragma unroll
                for (int nf = 0; nf < 4; ++nf) {
                    acc[mf][nf] = __builtin_amdgcn_mfma_f32_16x16x32_bf16(
                        af[mf][0], bfr[nf][0], acc[mf][nf], 0, 0, 0);
                    if constexpr (SPLIT) {
                        acc[mf][nf] = __builtin_amdgcn_mfma_f32_16x16x32_bf16(
                            af[mf][0], bfr[nf][1], acc[mf][nf], 0, 0, 0);
                        acc[mf][nf] = __builtin_amdgcn_mfma_f32_16x16x32_bf16(
                            af[mf][1], bfr[nf][0], acc[mf][nf], 0, 0, 0);
                    }
                }
        }
    }

    // ---- epilogue: C row = lg*4+r, col = lr within each 16x16 subtile ----
    float colred[4];
    if constexpr (OMODE == 4) {
        colred[0] = colred[1] = colred[2] = colred[3] = -3.402823466e38f;
    } else if constexpr (OMODE == 5) {
        colred[0] = colred[1] = colred[2] = colred[3] = 0.0f;
    }
    #pragma unroll
    for (int mf = 0; mf < MF; ++mf)
        #pragma unroll
        for (int nf = 0; nf < 4; ++nf) {
            int col  = n0 + noff + nf * 16 + lr;
            int mrow = m0 + moff + mf * 16 + lg * 4;
            float bv = bias ? bias[col] : 0.0f;
            float ov[4];
            #pragma unroll
            for (int r = 0; r < 4; ++r) ov[r] = acc[mf][nf][r] + bv;
            if constexpr (OMODE == 0) {
                #pragma unroll
                for (int r = 0; r < 4; ++r) {
                    float o = ov[r];
                    if constexpr (DO_GELU) o = gelu_f(o);
                    Cf[(size_t)(mrow + r) * N + col] = o;
                }
            } else if constexpr (OMODE == 1) {
                #pragma unroll
                for (int r = 0; r < 4; ++r) {
                    float o = ov[r];
                    if constexpr (DO_GELU) o = gelu_f(o);
                    u16 hb, lb; split_bf(o, hb, lb);
                    O1h[(size_t)(mrow + r) * N + col] = hb;
                    O1l[(size_t)(mrow + r) * N + col] = lb;
                }
            } else if constexpr (OMODE == 3) {
                if (col < partN) {
                    #pragma unroll
                    for (int r = 0; r < 4; ++r) {
                        u16 hb, lb; split_bf(ov[r], hb, lb);
                        O1h[(size_t)(mrow + r) * partN + col] = hb;
                        O1l[(size_t)(mrow + r) * partN + col] = lb;
                    }
                } else if (col < 2 * partN) {
                    int c2 = col - partN;
                    #pragma unroll
                    for (int r = 0; r < 4; ++r) {
                        u16 hb, lb; split_bf(ov[r], hb, lb);
                        O2h[(size_t)(mrow + r) * partN + c2] = hb;
                        O2l[(size_t)(mrow + r) * partN + c2] = lb;
                    }
                } else {
                    int c2 = col - 2 * partN;
                    int hh = c2 >> 7, dd = c2 & 127;
                    int bb = mrow >> 10, s0 = mrow & 1023;
                    size_t idx = ((size_t)(bb * HH + hh) * 128 + dd) * 1024 + s0;
                    ushort4 oh, ol;
                    #pragma unroll
                    for (int r = 0; r < 4; ++r) {
                        u16 hb, lb; split_bf(ov[r], hb, lb);
                        ((u16*)&oh)[r] = hb; ((u16*)&ol)[r] = lb;
                    }
                    *(ushort4*)&O3h[idx] = oh;
                    *(ushort4*)&O3l[idx] = ol;
                }
            } else if constexpr (OMODE == 4) {
                if (n0 < partN) {
                    #pragma unroll
                    for (int r = 0; r < 4; ++r)
                        colred[nf] = fmaxf(colred[nf], ov[r]);
                } else {
                    int c2 = col - partN;
                    #pragma unroll
                    for (int r = 0; r < 4; ++r) {
                        float o = gelu_f(ov[r]);
                        u16 hb, lb; split_bf(o, hb, lb);
                        O1h[(size_t)(mrow + r) * partN + c2] = hb;
                        O1l[(size_t)(mrow + r) * partN + c2] = lb;
                    }
                }
            } else if constexpr (OMODE == 5) {
                #pragma unroll
                for (int r = 0; r < 4; ++r) {
                    float o = gelu_f(ov[r]);
                    colred[nf] += o;
                    u16 hb, lb; split_bf(o, hb, lb);
                    O1h[(size_t)(mrow + r) * N + col] = hb;
                    O1l[(size_t)(mrow + r) * N + col] = lb;
                }
            }
        }
    // ---- fixed-order per-block column reduction (deterministic) ----
    if constexpr (OMODE == 4 || OMODE == 5) {
        bool doRed = (OMODE == 5) || (n0 < partN);
        if (doRed) {
            __syncthreads();
            float* sred = (float*)&As[0][0];   // 4 KB scratch, tile dead
            #pragma unroll
            for (int nf = 0; nf < 4; ++nf) sred[t * 4 + nf] = colred[nf];
            __syncthreads();
            if (t < 128) {
                int cl = t, lrr = cl & 15, nff = (cl & 63) >> 4, wb = cl >> 6;
                float a = (OMODE == 4) ? -3.402823466e38f : 0.0f;
                #pragma unroll
                for (int k2 = 0; k2 < 2; ++k2)
                    #pragma unroll
                    for (int l2 = 0; l2 < 4; ++l2) {
                        float v = sred[(((wb + 2 * k2) * 64) + l2 * 16 + lrr) * 4 + nff];
                        if constexpr (OMODE == 4) a = fmaxf(a, v); else a += v;
                    }
                int stride = (OMODE == 4) ? partN : N;
                Cf[(size_t)blockIdx.y * stride + n0 + cl] = a;
            }
        }
    }
}

// ---------------------------------------------------------------------------
// Plane flash attention (R4/R10-proven, NW=4) + XCD swizzle (T1).
// ---------------------------------------------------------------------------
__global__ __launch_bounds__(256, 3)
void attn_planes(const u16* __restrict__ Qh, const u16* __restrict__ Ql,
                 const u16* __restrict__ Kh, const u16* __restrict__ Kl,
                 const u16* __restrict__ Vh, const u16* __restrict__ Vl,
                 u16* __restrict__ Oh, u16* __restrict__ Ol,
                 int S, int Dm, int H, float scale)
{
    __shared__ __align__(16) u16 KsL[2][32 * 136];
    __shared__ __align__(16) u16 VsL[2][128 * 40];
    __shared__ __align__(16) u16 PsL[2][4 * 16 * 40];
    const int t = threadIdx.x, w = t >> 6, l = t & 63;
    const int lr = l & 15, lg = l >> 4;
    const int nqt = gridDim.x;
    const int nwg = nqt * gridDim.y;
    const int fid = blockIdx.y * nqt + blockIdx.x;
    const int nid = (fid & 7) * (nwg >> 3) + (fid >> 3);
    const int bh = nid / nqt, qt = nid - bh * nqt;
    const int b = bh / H, h = bh - b * H;
    const int q0 = qt * 64 + w * 16;
    const size_t qkbase = (size_t)(b * S) * Dm + h * 128;
    const size_t vbase  = (size_t)(b * H + h) * 128 * 1024;

    short8 qhf[4], qlf[4];
    #pragma unroll
    for (int ks = 0; ks < 4; ++ks) {
        size_t g = qkbase + (size_t)(q0 + lr) * Dm + ks * 32 + lg * 8;
        qhf[ks] = *(const short8*)&Qh[g];
        qlf[ks] = *(const short8*)&Ql[g];
    }
    f32x4 accO[8];
    #pragma unroll
    for (int i = 0; i < 8; ++i) accO[i] = 0.0f;
    float ls = 0.0f;
    const int pw = w * 640;

    for (int c0 = 0; c0 < S; c0 += 32) {
        __syncthreads();
        #pragma unroll
        for (int p = 0; p < 2; ++p) {
            int key = p * 16 + (t >> 4);
            int slot = t & 15;
            size_t g = qkbase + (size_t)(c0 + key) * Dm + slot * 8;
            *(uint4*)&KsL[0][key * 136 + slot * 8] = *(const uint4*)&Kh[g];
            *(uint4*)&KsL[1][key * 136 + slot * 8] = *(const uint4*)&Kl[g];
        }
        #pragma unroll
        for (int p = 0; p < 2; ++p) {
            int d = p * 64 + (t >> 2);
            int ksl = t & 3;
            size_t g = vbase + (size_t)d * 1024 + c0 + ksl * 8;
            *(uint4*)&VsL[0][d * 40 + ksl * 8] = *(const uint4*)&Vh[g];
            *(uint4*)&VsL[1][d * 40 + ksl * 8] = *(const uint4*)&Vl[g];
        }
        __syncthreads();
        f32x4 sac[2];
        sac[0] = 0.0f; sac[1] = 0.0f;
        #pragma unroll
        for (int mt = 0; mt < 2; ++mt)
            #pragma unroll
            for (int ks = 0; ks < 4; ++ks) {
                int a = (mt * 16 + lr) * 136 + ks * 32 + lg * 8;
                short8 khf = *(const short8*)&KsL[0][a];
                short8 klf = *(const short8*)&KsL[1][a];
                sac[mt] = __builtin_amdgcn_mfma_f32_16x16x32_bf16(khf, qhf[ks], sac[mt], 0, 0, 0);
                sac[mt] = __builtin_amdgcn_mfma_f32_16x16x32_bf16(khf, qlf[ks], sac[mt], 0, 0, 0);
                sac[mt] = __builtin_amdgcn_mfma_f32_16x16x32_bf16(klf, qhf[ks], sac[mt], 0, 0, 0);
            }
        #pragma unroll
        for (int mt = 0; mt < 2; ++mt)
            #pragma unroll
            for (int rr = 0; rr < 4; ++rr) {
                float p = __expf(sac[mt][rr] * scale);
                ls += p;
                int key = mt * 16 + lg * 4 + rr;
                u16 hb, lb; split_bf(p, hb, lb);
                PsL[0][pw + lr * 40 + key] = hb;
                PsL[1][pw + lr * 40 + key] = lb;
            }
        short8 pah = *(const short8*)&PsL[0][pw + lr * 40 + lg * 8];
        short8 pal = *(const short8*)&PsL[1][pw + lr * 40 + lg * 8];
        #pragma unroll
        for (int nt = 0; nt < 8; ++nt) {
            int a = (nt * 16 + lr) * 40 + lg * 8;
            short8 vhf = *(const short8*)&VsL[0][a];
            short8 vlf = *(const short8*)&VsL[1][a];
            accO[nt] = __builtin_amdgcn_mfma_f32_16x16x32_bf16(pah, vhf, accO[nt], 0, 0, 0);
            accO[nt] = __builtin_amdgcn_mfma_f32_16x16x32_bf16(pah, vlf, accO[nt], 0, 0, 0);
            accO[nt] = __builtin_amdgcn_mfma_f32_16x16x32_bf16(pal, vhf, accO[nt], 0, 0, 0);
        }
    }
    float lt = ls + __shfl_xor(ls, 16, 64);
    lt += __shfl_xor(lt, 32, 64);
    #pragma unroll
    for (int rr = 0; rr < 4; ++rr) {
        float inv = 1.0f / __shfl(lt, lg * 4 + rr, 64);
        size_t rowoff = qkbase + (size_t)(q0 + lg * 4 + rr) * Dm;
        #pragma unroll
        for (int nt = 0; nt < 8; ++nt) {
            float o = accO[nt][rr] * inv;
            u16 hb, lb; split_bf(o, hb, lb);
            Oh[rowoff + nt * 16 + lr] = hb;
            Ol[rowoff + nt * 16 + lr] = lb;
        }
    }
}

// ---------------------------------------------------------------------------
// Multi-segment packer: fp32 -> bf16 hi/lo planes. n4 = count of float4s.
// ---------------------------------------------------------------------------
struct PSeg { const float* s; u16* h; u16* l; int n4; int pad; };
struct PArgs { PSeg g[8]; };

__global__ __launch_bounds__(256)
void pack_many(PArgs a)
{
    PSeg sg = a.g[blockIdx.y];
    int i = blockIdx.x * 256 + threadIdx.x;
    if (i >= sg.n4) return;
    float4 v = *(const float4*)&sg.s[i * 4];
    ushort4 hv, lv;
    split_bf(v.x, hv.x, lv.x);
    split_bf(v.y, hv.y, lv.y);
    split_bf(v.z, hv.z, lv.z);
    split_bf(v.w, hv.w, lv.w);
    *(ushort4*)&sg.h[i * 4] = hv;
    *(ushort4*)&sg.l[i * 4] = lv;
}

__global__ __launch_bounds__(256)
void pack_f32(const float* __restrict__ src, u16* __restrict__ dh,
              u16* __restrict__ dl, int n4)
{
    int i = blockIdx.x * 256 + threadIdx.x;
    if (i >= n4) return;
    float4 v = *(const float4*)&src[i * 4];
    ushort4 hv, lv;
    split_bf(v.x, hv.x, lv.x);
    split_bf(v.y, hv.y, lv.y);
    split_bf(v.z, hv.z, lv.z);
    split_bf(v.w, hv.w, lv.w);
    *(ushort4*)&dh[i * 4] = hv;
    *(ushort4*)&dl[i * 4] = lv;
}

__global__ __launch_bounds__(256)
void packT64(const float* __restrict__ src, u16* __restrict__ dh,
             u16* __restrict__ dl, int R, int C)
{
    __shared__ float tile[64][65];
    int r0 = blockIdx.y * 64, c0 = blockIdx.x * 64;
    int t = threadIdx.x;
    #pragma unroll
    for (int i = 0; i < 16; ++i) {
        int idx = i * 256 + t, rr = idx >> 6, cc = idx & 63;
        tile[rr][cc] = src[(size_t)(r0 + rr) * C + c0 + cc];
    }
    __syncthreads();
    #pragma unroll
    for (int i = 0; i < 16; ++i) {
        int idx = i * 256 + t, rr = idx >> 6, cc = idx & 63;
        float v = tile[cc][rr];
        u16 hb, lb; split_bf(v, hb, lb);
        size_t o = (size_t)(c0 + rr) * R + r0 + cc;
        dh[o] = hb; dl[o] = lb;
    }
}

// concat biases: rbias[3072], ibias[1536], apbias[1024] (aff_b | zeros)
__global__ __launch_bounds__(1024)
void concat_bias(const float* rq, const float* rk, const float* rv,
                 const float* iq, const float* ik, const float* iv,
                 const float* ab, float* rb, float* ib, float* apb)
{
    int t = threadIdx.x;
    rb[t]        = rq[t];
    rb[1024 + t] = rk[t];
    rb[2048 + t] = rv[t];
    apb[t] = (t < 512) ? ab[t] : 0.0f;
    if (t < 512) {
        ib[t]        = iq[t];
        ib[512 + t]  = ik[t];
        ib[1024 + t] = iv[t];
    }
}

__global__ __launch_bounds__(256)
void mask_rows(u16* __restrict__ ph, const float* __restrict__ mask)
{
    int i = blockIdx.x * 256 + threadIdx.x;
    int i4 = i * 4;
    int bb = i4 >> 20;
    int col = i4 & 1023;
    ushort4 v = *(ushort4*)&ph[i4];
    float4 m = *(const float4*)&mask[bb * 1024 + col];
    if (m.x == 0.f) v.x = 0;
    if (m.y == 0.f) v.y = 0;
    if (m.z == 0.f) v.z = 0;
    if (m.w == 0.f) v.w = 0;
    *(ushort4*)&ph[i4] = v;
}

// ---------------------------------------------------------------------------
// Fused partial-reduce (8 row-blocks, fixed order) + top-K mask via BITONIC
// sort (val desc, idx asc = jax.lax.top_k tie semantics). R12's rank-count
// variant was O(N) serial work per thread (~20 µs on a 4-block grid); bitonic
// is log^2(N) ~ 55 stages per thread. OP: 0=max, 1=sum (positive scale is
// rank-invariant, so the 1/S factor is dropped).
// ---------------------------------------------------------------------------
template<int N, int KSEL, int OP>
__global__ __launch_bounds__(1024)
void topk_fused(const float* __restrict__ P, float* __restrict__ mask)
{
    __shared__ float v[N];
    __shared__ int   id[N];
    int t = threadIdx.x;
    int b = blockIdx.x;
    float a = (OP == 0) ? -3.402823466e38f : 0.0f;
    #pragma unroll
    for (int r = 0; r < 8; ++r) {
        float x = P[(size_t)(b * 8 + r) * N + t];
        if (OP == 0) a = fmaxf(a, x); else a += x;
    }
    v[t]  = a;
    id[t] = t;
    __syncthreads();
    for (int k = 2; k <= N; k <<= 1) {
        for (int j = k >> 1; j > 0; j >>= 1) {
            int ixj = t ^ j;
            if (ixj > t) {
                bool dir = ((t & k) == 0);
                float va = v[t], vb = v[ixj];
                int   ia = id[t], ib = id[ixj];
                bool before_b = (vb > va) || (vb == va && ib < ia);
                bool sw = dir ? before_b : !before_b;
                if (sw) { v[t] = vb; v[ixj] = va; id[t] = ib; id[ixj] = ia; }
            }
            __syncthreads();
        }
    }
    mask[b * N + id[t]] = (t < KSEL) ? 1.0f : 0.0f;
}

__global__ __launch_bounds__(256)
void ln_mask_planes(const u16* __restrict__ Xh, const u16* __restrict__ Xl,
                    const u16* __restrict__ Rh, const u16* __restrict__ Rl,
                    const float* __restrict__ gam, const float* __restrict__ bet,
                    const float* __restrict__ mask,
                    u16* __restrict__ Yh, u16* __restrict__ Yl)
{
    int row = blockIdx.x, bb = row >> 10, t = threadIdx.x;
    size_t base = (size_t)row * 512;
    float a1 = bf2f(Xh[base + t]) + bf2f(Xl[base + t])
             + bf2f(Rh[base + t]) + bf2f(Rl[base + t]);
    float a2 = bf2f(Xh[base + t + 256]) + bf2f(Xl[base + t + 256])
             + bf2f(Rh[base + t + 256]) + bf2f(Rl[base + t + 256]);
    float s  = a1 + a2;
    float sq = a1 * a1 + a2 * a2;
    #pragma unroll
    for (int off = 32; off > 0; off >>= 1) {
        s  += __shfl_down(s, off, 64);
        sq += __shfl_down(sq, off, 64);
    }
    __shared__ float red[8];
    int wid = t >> 6, lane = t & 63;
    if (lane == 0) { red[wid] = s; red[wid + 4] = sq; }
    __syncthreads();
    if (t == 0) {
        float st  = red[0] + red[1] + red[2] + red[3];
        float sqt = red[4] + red[5] + red[6] + red[7];
        float mu  = st / 512.0f;
        float var = sqt / 512.0f - mu * mu;
        red[0] = mu;
        red[1] = rsqrtf(var + 1e-5f);
    }
    __syncthreads();
    float mu = red[0], rstd = red[1];
    float y1 = ((a1 - mu) * rstd * gam[t] + bet[t]) * mask[bb * 512 + t];
    float y2 = ((a2 - mu) * rstd * gam[t + 256] + bet[t + 256]) * mask[bb * 512 + t + 256];
    u16 hb, lb;
    split_bf(y1, hb, lb); Yh[base + t] = hb;       Yl[base + t] = lb;
    split_bf(y2, hb, lb); Yh[base + t + 256] = hb; Yl[base + t + 256] = lb;
}

// ---------------------------------------------------------------------------
extern "C" void kernel_launch(void* const* d_in, const int* in_sizes, int n_in,
                              void* d_out, int out_size, void* d_ws, size_t ws_size,
                              hipStream_t stream)
{
    (void)in_sizes; (void)n_in; (void)out_size; (void)ws_size;
    const float* x        = (const float*)d_in[0];
    const float* r_wq     = (const float*)d_in[1];
    const float* r_wk     = (const float*)d_in[2];
    const float* r_wv     = (const float*)d_in[3];
    const float* r_bq     = (const float*)d_in[4];
    const float* r_bk     = (const float*)d_in[5];
    const float* r_bv     = (const float*)d_in[6];
    const float* r_wo     = (const float*)d_in[7];
    const float* r_bo     = (const float*)d_in[8];
    const float* aff_w    = (const float*)d_in[9];
    const float* aff_b    = (const float*)d_in[10];
    const float* patterns = (const float*)d_in[11];
    const float* i_wq     = (const float*)d_in[12];
    const float* i_wk     = (const float*)d_in[13];
    const float* i_wv     = (const float*)d_in[14];
    const float* i_bq     = (const float*)d_in[15];
    const float* i_bk     = (const float*)d_in[16];
    const float* i_bv     = (const float*)d_in[17];
    const float* i_wo     = (const float*)d_in[18];
    const float* i_bo     = (const float*)d_in[19];
    const float* ln_g     = (const float*)d_in[20];
    const float* ln_b     = (const float*)d_in[21];
    const float* comb_w   = (const float*)d_in[22];
    const float* proj_w   = (const float*)d_in[23];

    constexpr size_t MBy = 1024 * 1024;
    char* base = (char*)d_ws;

    // region A 0-16MB: x planes -> ap planes -> { comb/proj weights (0-6) | act (8-16) }
    u16* xh   = (u16*)(base);             u16* xl   = (u16*)(base + 8 * MBy);
    u16* aph  = xh;                        u16* apl  = xl;
    u16* cbh  = (u16*)(base);             u16* cbl  = (u16*)(base + 1 * MBy);
    u16* pjh  = (u16*)(base + 2 * MBy);   u16* pjl  = (u16*)(base + 4 * MBy);
    u16* acth = (u16*)(base + 8 * MBy);   u16* actl = (u16*)(base + 12 * MBy);
    // region B 16-32MB: rq -> ctx -> pa
    u16* rqh  = (u16*)(base + 16 * MBy);  u16* rql  = (u16*)(base + 24 * MBy);
    u16* ctxh = rqh;                       u16* ctxl = rql;
    u16* pah  = rqh;                       u16* pal  = rql;
    // region C 32-48MB: rk -> iq/ik -> a2f/lnm
    u16* rkh  = (u16*)(base + 32 * MBy);  u16* rkl  = (u16*)(base + 40 * MBy);
    u16* iqh  = (u16*)(base + 32 * MBy);  u16* iql  = (u16*)(base + 36 * MBy);
    u16* ikh  = (u16*)(base + 40 * MBy);  u16* ikl  = (u16*)(base + 44 * MBy);
    u16* a2fh = iqh;                       u16* a2fl = iql;
    u16* lnmh = ikh;                       u16* lnml = ikl;
    // region D 48-64MB: rvt -> ivt / a2p
    u16* rvth = (u16*)(base + 48 * MBy);  u16* rvtl = (u16*)(base + 56 * MBy);
    u16* ivth = (u16*)(base + 48 * MBy);  u16* ivtl = (u16*)(base + 52 * MBy);
    u16* a2ph = (u16*)(base + 56 * MBy);  u16* a2pl = (u16*)(base + 60 * MBy);
    // region E 64-76MB: weights. wave1: router QKV (12MB). wave2a after QKV:
    u16* wqkvh  = (u16*)(base + 64 * MBy); u16* wqkvl = (u16*)(base + 70 * MBy);
    u16* woh    = (u16*)(base + 64 * MBy); u16* wol   = (u16*)(base + 66 * MBy);
    u16* apbh   = (u16*)(base + 68 * MBy); u16* apbl  = (u16*)(base + 70 * MBy);
    u16* iwqkvh = (u16*)(base + 72 * MBy);
    u16* iwqkvl = (u16*)(base + 72 * MBy + 1572864);   // +1.5MB
    u16* iwoh   = (u16*)(base + 75 * MBy);
    u16* iwol   = (u16*)(base + 75 * MBy + 524288);    // +0.5MB
    // region F 76MB+: smalls
    float* partial = (float*)(base + 76 * MBy);                 // 128 KB max
    float* maskI   = (float*)(base + 76 * MBy + 262144);
    float* maskP   = maskI + 2048;
    float* rbias   = maskP + 4096;        // 3072 f32
    float* ibias   = rbias + 3072;        // 1536 f32
    float* apbias  = ibias + 1536;        // 1024 f32

    const float scale = 0.08838834764831843f;  // 1/sqrt(128)
    dim3 blk(256);

    // --- biases + wave-1 packs (x, router QKV weights) in 2 dispatches ---
    concat_bias<<<dim3(1), dim3(1024), 0, stream>>>(r_bq, r_bk, r_bv,
        i_bq, i_bk, i_bv, aff_b, rbias, ibias, apbias);
    {
        PArgs a{};
        a.g[0] = {x,    xh,              xl,              1048576, 0};
        a.g[1] = {r_wq, wqkvh,           wqkvl,           262144,  0};
        a.g[2] = {r_wk, wqkvh + 1048576, wqkvl + 1048576, 262144,  0};
        a.g[3] = {r_wv, wqkvh + 2097152, wqkvl + 2097152, 262144,  0};
        pack_many<<<dim3(4096, 4), blk, 0, stream>>>(a);
    }

    // --- router fused QKV GEMM (Q,K planes + V transposed planes) ---
    gemm_planes<128, true, false, 3><<<dim3(24, 32), blk, 0, stream>>>(
        xh, xl, wqkvh, wqkvl, rbias, nullptr,
        rqh, rql, rkh, rkl, rvth, rvtl, 4096, 3072, 1024, 8, 1024);

    // --- wave-2a packs (wqkv dead): wo, aff|patterns CONCAT, i_w* CONCAT ---
    {
        PArgs a{};
        a.g[0] = {r_wo,     woh,             wol,             262144, 0};
        a.g[1] = {aff_w,    apbh,            apbl,            131072, 0};
        a.g[2] = {patterns, apbh + 524288,   apbl + 524288,   131072, 0};
        a.g[3] = {i_wq,     iwqkvh,          iwqkvl,          65536,  0};
        a.g[4] = {i_wk,     iwqkvh + 262144, iwqkvl + 262144, 65536,  0};
        a.g[5] = {i_wv,     iwqkvh + 524288, iwqkvl + 524288, 65536,  0};
        a.g[6] = {i_wo,     iwoh,            iwol,            65536,  0};
        pack_many<<<dim3(1024, 7), blk, 0, stream>>>(a);
    }

    attn_planes<<<dim3(16, 32), blk, 0, stream>>>(rqh, rql, rkh, rkl, rvth, rvtl,
                                                  aph, apl, 1024, 1024, 8, scale);
    gemm_planes<128, true, false, 1><<<dim3(8, 32), blk, 0, stream>>>(
        aph, apl, woh, wol, r_bo, nullptr,
        ctxh, ctxl, nullptr, nullptr, nullptr, nullptr, 4096, 1024, 1024, 0, 0);

    // --- fused affinity-max partials | gelu(patterns) act planes ---
    gemm_planes<128, true, false, 4><<<dim3(8, 32), blk, 0, stream>>>(
        ctxh, ctxl, apbh, apbl, apbias, partial,
        acth, actl, nullptr, nullptr, nullptr, nullptr, 4096, 1024, 1024, 0, 512);
    topk_fused<512, 256, 0><<<dim3(4), dim3(512), 0, stream>>>(partial, maskI);

    // --- wave-2b packs (region A front free after wo GEMM): comb, proj^T ---
    pack_f32<<<512, blk, 0, stream>>>(comb_w, cbh, cbl, 131072);
    packT64<<<dim3(16, 16), blk, 0, stream>>>(proj_w, pjh, pjl, 1024, 1024);

    // --- InputNeurons ---
    gemm_planes<128, true, false, 3><<<dim3(12, 32), blk, 0, stream>>>(
        acth, actl, iwqkvh, iwqkvl, ibias, nullptr,
        iqh, iql, ikh, ikl, ivth, ivtl, 4096, 1536, 512, 4, 512);
    attn_planes<<<dim3(16, 16), blk, 0, stream>>>(iqh, iql, ikh, ikl, ivth, ivtl,
                                                  a2ph, a2pl, 1024, 512, 4, scale);
    gemm_planes<64, true, false, 1><<<dim3(8, 32), blk, 0, stream>>>(
        a2ph, a2pl, iwoh, iwol, i_bo, nullptr,
        a2fh, a2fl, nullptr, nullptr, nullptr, nullptr, 4096, 512, 512, 0, 0);
    ln_mask_planes<<<dim3(4096), blk, 0, stream>>>(acth, actl, a2fh, a2fl,
                                                   ln_g, ln_b, maskI, lnmh, lnml);

    // --- ProcessNeurons: comb GEMM + fused column-sum partials ---
    gemm_planes<128, true, true, 5><<<dim3(8, 32), blk, 0, stream>>>(
        lnmh, lnml, cbh, cbl, nullptr, partial,
        pah, pal, nullptr, nullptr, nullptr, nullptr, 4096, 1024, 512, 0, 0);
    topk_fused<1024, 512, 1><<<dim3(4), dim3(1024), 0, stream>>>(partial, maskP);
    mask_rows<<<4096, blk, 0, stream>>>(pah, maskP);

    // --- final projection (hi planes only, 1 MFMA) ---
    gemm_planes<128, false, false, 0><<<dim3(8, 32), blk, 0, stream>>>(
        pah, nullptr, pjh, nullptr, nullptr, (float*)d_out,
        nullptr, nullptr, nullptr, nullptr, nullptr, nullptr, 4096, 1024, 1024, 0, 0);
}